// Round 6
// baseline (793.525 us; speedup 1.0000x reference)
//
#include <hip/hip_runtime.h>
#include <math.h>

#define HIMG 512
#define WIMG 640
#define NPIX (HIMG*WIMG)      // 327680
#define HF 64
#define WF 80
#define NFP (HF*WF)           // 5120
#define DH 128
#define CF 32
#define NV 5

// ---- workspace layout (float offsets) ----
#define SZ_X1   (5u*8u*256u*320u)        // 3,276,800
#define SZ_X2   (5u*16u*128u*160u)       // 1,638,400
#define SZ_FE   (5u*NFP*CF)              // 819,200
#define SZ_WP   48u
#define SZ_COST ((unsigned)DH*HF*CF*WF)  // 20,971,520
#define SZ_R1   ((unsigned)DH*HF*8u*WF)  // 5,242,880
#define SZ_C2   ((unsigned)DH*NFP)       // 655,360

#define OFF_X1   0u
#define OFF_X2   (OFF_X1+SZ_X1)
#define OFF_FE   (OFF_X2+SZ_X2)
#define OFF_WP   (OFF_FE+SZ_FE)
#define OFF_COST (OFF_WP+SZ_WP)
#define OFF_R1   (OFF_COST+SZ_COST)
#define OFF_C2   (OFF_R1+SZ_R1)
#define OFF_RL   (OFF_C2+SZ_C2)
#define OFF_CL   (OFF_RL+NFP)
#define OFF_RU   (OFF_CL+NFP)

__device__ __forceinline__ int iclamp(int v, int lo, int hi){ return v<lo?lo:(v>hi?hi:v); }

// ---------------- homography setup (1 thread) ----------------
__global__ void k_setup(const float* __restrict__ Kin, const float* __restrict__ poses,
                        float* __restrict__ warp) {
  if (threadIdx.x != 0 || blockIdx.x != 0) return;
  float Kf[9];
  for (int i=0;i<9;i++) Kf[i]=Kin[i];
  for (int i=0;i<6;i++) Kf[i]*=0.125f;
  float a=Kf[0],b=Kf[1],c=Kf[2],d=Kf[3],e=Kf[4],f=Kf[5],g=Kf[6],h=Kf[7],ii=Kf[8];
  float det=a*(e*ii-f*h)-b*(d*ii-f*g)+c*(d*h-e*g);
  float id=1.0f/det;
  float Ki[9]={(e*ii-f*h)*id,(c*h-b*ii)*id,(b*f-c*e)*id,
               (f*g-d*ii)*id,(a*ii-c*g)*id,(c*d-a*f)*id,
               (d*h-e*g)*id,(b*g-a*h)*id,(a*e-b*d)*id};
  float R0[9]={poses[0],poses[1],poses[2],poses[4],poses[5],poses[6],poses[8],poses[9],poses[10]};
  float t0[3]={poses[3],poses[7],poses[11]};
  for (int v=1; v<NV; v++) {
    const float* P=poses+16*v;
    float Rv[9]={P[0],P[1],P[2],P[4],P[5],P[6],P[8],P[9],P[10]};
    float tv[3]={P[3],P[7],P[11]};
    float TR[9], Tt[3], M[9], A[9], bb[3];
    for (int r=0;r<3;r++)
      for (int cc=0;cc<3;cc++)
        TR[r*3+cc]=Rv[r*3+0]*R0[cc*3+0]+Rv[r*3+1]*R0[cc*3+1]+Rv[r*3+2]*R0[cc*3+2];
    for (int r=0;r<3;r++)
      Tt[r]=tv[r]-(TR[r*3+0]*t0[0]+TR[r*3+1]*t0[1]+TR[r*3+2]*t0[2]);
    for (int r=0;r<3;r++)
      for (int cc=0;cc<3;cc++)
        M[r*3+cc]=TR[r*3+0]*Ki[0*3+cc]+TR[r*3+1]*Ki[1*3+cc]+TR[r*3+2]*Ki[2*3+cc];
    for (int r=0;r<3;r++)
      for (int cc=0;cc<3;cc++)
        A[r*3+cc]=Kf[r*3+0]*M[0*3+cc]+Kf[r*3+1]*M[1*3+cc]+Kf[r*3+2]*M[2*3+cc];
    for (int r=0;r<3;r++)
      bb[r]=Kf[r*3+0]*Tt[0]+Kf[r*3+1]*Tt[1]+Kf[r*3+2]*Tt[2];
    float* o=warp+(v-1)*12;
    for (int i=0;i<9;i++) o[i]=A[i];
    for (int r=0;r<3;r++) o[9+r]=bb[r];
  }
}

// ---------------- encoder conv1: 3->8 stride2, relu ----------------
__global__ __launch_bounds__(256) void k_conv1(const float* __restrict__ img,
    const float* __restrict__ w, const float* __restrict__ bias, float* __restrict__ x1) {
  __shared__ float wl[216];
  int tid=threadIdx.x;
  for (int i=tid;i<216;i+=256){
    int oc=i&7; int rest=i>>3; int kx=rest%3; int ky=(rest/3)%3; int ic=rest/9;
    wl[i]=w[((oc*3+ic)*3+ky)*3+kx];
  }
  __syncthreads();
  int t=blockIdx.x*256+tid;
  int n=t/81920; int r=t%81920; int oy=r/320; int ox=r%320;
  float acc[8];
  #pragma unroll
  for (int oc=0;oc<8;oc++) acc[oc]=bias[oc];
  for (int ic=0;ic<3;ic++){
    const float* ip = img + (n*3+ic)*NPIX;
    #pragma unroll
    for (int ky=0;ky<3;ky++){
      int iy=2*oy+ky; if (iy>=HIMG) continue;
      #pragma unroll
      for (int kx=0;kx<3;kx++){
        int ix=2*ox+kx; if (ix>=WIMG) continue;
        float v=ip[iy*WIMG+ix];
        const float* ww=&wl[((ic*3+ky)*3+kx)*8];
        #pragma unroll
        for (int oc=0;oc<8;oc++) acc[oc]+=v*ww[oc];
      }
    }
  }
  float* op = x1 + (n*8)*81920 + oy*320+ox;
  #pragma unroll
  for (int oc=0;oc<8;oc++){ float vv=fmaxf(acc[oc],0.0f); op[oc*81920]=vv; }
}

// ---------------- encoder conv2: 8->16 stride2, relu ----------------
__global__ __launch_bounds__(256) void k_conv2(const float* __restrict__ x1,
    const float* __restrict__ w, const float* __restrict__ bias, float* __restrict__ x2){
  __shared__ float wl[1152];
  int tid=threadIdx.x;
  for (int i=tid;i<1152;i+=256){
    int oc=i&15; int rest=i>>4; int tap=rest%9; int ic=rest/9;
    int ky=tap/3, kx=tap%3;
    wl[i]=w[((oc*8+ic)*3+ky)*3+kx];
  }
  __syncthreads();
  int t=blockIdx.x*256+tid;
  int n=t/20480; int r=t%20480; int oy=r/160; int ox=r%160;
  float acc[16];
  #pragma unroll
  for (int oc=0;oc<16;oc++) acc[oc]=bias[oc];
  for (int ic=0;ic<8;ic++){
    const float* ip=x1+(n*8+ic)*81920;
    #pragma unroll
    for (int ky=0;ky<3;ky++){
      int iy=2*oy+ky; if(iy>=256) continue;
      #pragma unroll
      for (int kx=0;kx<3;kx++){
        int ix=2*ox+kx; if(ix>=320) continue;
        float v=ip[iy*320+ix];
        const float* ww=&wl[(ic*9+ky*3+kx)*16];
        #pragma unroll
        for (int oc=0;oc<16;oc++) acc[oc]+=v*ww[oc];
      }
    }
  }
  float* op=x2+(n*16)*20480+oy*160+ox;
  #pragma unroll
  for (int oc=0;oc<16;oc++){ float vv=fmaxf(acc[oc],0.0f); op[oc*20480]=vv; }
}

// ---------------- encoder conv3: 16->32 stride2, oc-split x2, channel-last out ----------------
__global__ __launch_bounds__(256) void k_conv3(const float* __restrict__ x2,
    const float* __restrict__ w, const float* __restrict__ bias, float* __restrict__ fe){
  __shared__ float wl[4608];
  int tid=threadIdx.x;
  for (int i=tid;i<4608;i+=256){
    int oc=i&31; int rest=i>>5; int tap=rest%9; int ic=rest/9;
    int ky=tap/3,kx=tap%3;
    wl[i]=w[((oc*16+ic)*3+ky)*3+kx];
  }
  __syncthreads();
  int t=blockIdx.x*256+tid;          // 51200
  int half=t&1; int r=t>>1;          // r: 0..25599
  int n=r/NFP; int p=r%NFP; int oy=p/WF; int ox=p%WF;
  float acc[16];
  #pragma unroll
  for (int oc=0;oc<16;oc++) acc[oc]=bias[half*16+oc];
  for (int ic=0;ic<16;ic++){
    const float* ip=x2+(n*16+ic)*20480;
    #pragma unroll
    for (int ky=0;ky<3;ky++){
      int iy=2*oy+ky; if(iy>=128) continue;
      #pragma unroll
      for (int kx=0;kx<3;kx++){
        int ix=2*ox+kx; if(ix>=160) continue;
        float v=ip[iy*160+ix];
        const float* ww=&wl[(ic*9+ky*3+kx)*32+half*16];
        #pragma unroll
        for (int oc=0;oc<16;oc++) acc[oc]+=v*ww[oc];
      }
    }
  }
  float* op=fe+(size_t)r*CF+half*16;
  #pragma unroll
  for (int q=0;q<4;q++) ((float4*)op)[q]=((float4*)acc)[q];
}

// ---------------- plane-sweep cost volume (variance) ----------------
// out layout: cost[((d*HF+y)*CF + c)*WF + x]
__global__ __launch_bounds__(256) void k_costvol(const float* __restrict__ fe,
    const float* __restrict__ warp, float* __restrict__ cost){
  int t=blockIdx.x*256+threadIdx.x;
  int x=t%WF; int y=(t/WF)&(HF-1); int d=t/NFP;
  float invd=2.0f-(float)d*(1.8f/127.0f);
  float depth=1.0f/invd;
  float s[32], ss[32];
  {
    const float4* q=(const float4*)(fe+(size_t)(y*WF+x)*CF);
    #pragma unroll
    for (int i=0;i<8;i++){
      float4 r=q[i];
      s[4*i+0]=r.x; ss[4*i+0]=r.x*r.x;
      s[4*i+1]=r.y; ss[4*i+1]=r.y*r.y;
      s[4*i+2]=r.z; ss[4*i+2]=r.z*r.z;
      s[4*i+3]=r.w; ss[4*i+3]=r.w*r.w;
    }
  }
  float fx=(float)x, fy=(float)y;
  for (int v=1; v<NV; v++){
    const float* W=warp+(v-1)*12;
    float u_=depth*(W[0]*fx+W[1]*fy+W[2])+W[9];
    float v_=depth*(W[3]*fx+W[4]*fy+W[5])+W[10];
    float z_=depth*(W[6]*fx+W[7]*fy+W[8])+W[11];
    float valid = (z_>0.001f)?1.0f:0.0f;
    float zc = (z_>0.001f)? z_ : 0.001f;
    float uu=u_/zc, vv=v_/zc;
    float fx0=floorf(uu), fy0=floorf(vv);
    float wx=uu-fx0, wy=vv-fy0;
    int xi=(int)fx0, yi=(int)fy0;
    float m00=((xi>=0)&&(xi<WF)&&(yi>=0)&&(yi<HF))?valid:0.0f;
    float m01=((xi+1>=0)&&(xi+1<WF)&&(yi>=0)&&(yi<HF))?valid:0.0f;
    float m10=((xi>=0)&&(xi<WF)&&(yi+1>=0)&&(yi+1<HF))?valid:0.0f;
    float m11=((xi+1>=0)&&(xi+1<WF)&&(yi+1>=0)&&(yi+1<HF))?valid:0.0f;
    float w00=(1.0f-wx)*(1.0f-wy)*m00, w01=wx*(1.0f-wy)*m01;
    float w10=(1.0f-wx)*wy*m10,       w11=wx*wy*m11;
    int xc0=iclamp(xi,0,WF-1), xc1=iclamp(xi+1,0,WF-1);
    int yc0=iclamp(yi,0,HF-1), yc1=iclamp(yi+1,0,HF-1);
    const float* fb=fe+(size_t)v*NFP*CF;
    const float4* q00=(const float4*)(fb+(size_t)(yc0*WF+xc0)*CF);
    const float4* q01=(const float4*)(fb+(size_t)(yc0*WF+xc1)*CF);
    const float4* q10=(const float4*)(fb+(size_t)(yc1*WF+xc0)*CF);
    const float4* q11=(const float4*)(fb+(size_t)(yc1*WF+xc1)*CF);
    #pragma unroll
    for (int i=0;i<8;i++){
      float4 A=q00[i], B=q01[i], C=q10[i], Dd=q11[i];
      float s0=w00*A.x+w01*B.x+w10*C.x+w11*Dd.x;
      float s1=w00*A.y+w01*B.y+w10*C.y+w11*Dd.y;
      float s2=w00*A.z+w01*B.z+w10*C.z+w11*Dd.z;
      float s3=w00*A.w+w01*B.w+w10*C.w+w11*Dd.w;
      s[4*i+0]+=s0; ss[4*i+0]+=s0*s0;
      s[4*i+1]+=s1; ss[4*i+1]+=s1*s1;
      s[4*i+2]+=s2; ss[4*i+2]+=s2*s2;
      s[4*i+3]+=s3; ss[4*i+3]+=s3*s3;
    }
  }
  float* cp=cost+((size_t)(d*HF+y)*CF)*WF+x;
  #pragma unroll
  for (int c=0;c<32;c++){
    float mean=s[c]*0.2f;
    float var=ss[c]*0.2f-mean*mean;
    cp[(size_t)c*WF]=var;
  }
}

// ---------------- reg1: conv3d 32->8 + relu; d-pair x4 per thread ----------------
// 1280 blocks x 64 thr = 5 waves/CU exactly. LDS-issue model: per (set,kh,ic,kw)
// 2 ds_read_b128 (~20cy/CU) vs 32 FMA-instr (16cy/CU) -> near-balanced.
// Runtime pi loop, single ic body, unroll 2 (round-4 spill lesson).
__global__ __launch_bounds__(64) void k_reg1(const float* __restrict__ cost,
    const float* __restrict__ w, const float* __restrict__ bias, float* __restrict__ r1) {
  __shared__ __align__(16) float wl[6912]; // [tap(kd,kh,kw)][ic][oc]
  int tid=threadIdx.x;
  for (int i=tid;i<6912;i+=64){
    int oc=i&7; int ic=(i>>3)&31; int tap=i>>8;
    int kd=tap/9; int rem=tap%9; int kh=rem/3; int kw=rem%3;
    wl[i]=w[(((oc*32+ic)*3+kd)*3+kh)*3+kw];
  }
  __syncthreads();
  int bid=blockIdx.x;
  int sb=(bid&7)*160 + (bid>>3);      // XCD d-swizzle: 160 contiguous per XCD
  int t=sb*64+tid;
  int xq=t%20; int y=(t/20)&63; int dq=t/1280;   // dq uniform per block (1280/64=20 blk/dq)
  int x0=xq*4;
  int d0=dq*2;
  float acc0[8][4], acc1[8][4];
  #pragma unroll
  for (int oc=0;oc<8;oc++){
    float bb=bias[oc];
    #pragma unroll
    for (int j=0;j<4;j++){ acc0[oc][j]=bb; acc1[oc][j]=bb; }
  }
  const float4* wq=(const float4*)wl;
  for (int pi=0; pi<4; ++pi){          // planes d0-1..d0+2, each read ONCE
    int dd=d0-1+pi;
    if (dd<0||dd>=DH) continue;        // block-uniform
    bool do0=(pi<3), do1=(pi>0);
    int tb0=pi*576;                    // float4 base: kd*9*64
    int tb1=(pi-1)*576;
    for (int kh=0;kh<3;kh++){
      int yy=y-1+kh; if (yy<0||yy>=HF) continue;
      const float* base=cost+((size_t)(dd*HF+yy)*CF)*WF+x0;
      int kb0=tb0+kh*192, kb1=tb1+kh*192;
      #pragma unroll 2
      for (int ic=0;ic<CF;ic++){
        const float* rr=base+(size_t)ic*WF;
        float in_[6];
        in_[0]=(x0>0)?rr[-1]:0.0f;
        in_[1]=rr[0]; in_[2]=rr[1]; in_[3]=rr[2]; in_[4]=rr[3];
        in_[5]=(x0<76)?rr[4]:0.0f;
        int icb=ic*2;
        #pragma unroll
        for (int kw=0;kw<3;kw++){
          if (do0){
            float4 wa=wq[kb0+kw*64+icb], wb=wq[kb0+kw*64+icb+1];
            #pragma unroll
            for (int j=0;j<4;j++){
              float v=in_[kw+j];
              acc0[0][j]+=v*wa.x; acc0[1][j]+=v*wa.y;
              acc0[2][j]+=v*wa.z; acc0[3][j]+=v*wa.w;
              acc0[4][j]+=v*wb.x; acc0[5][j]+=v*wb.y;
              acc0[6][j]+=v*wb.z; acc0[7][j]+=v*wb.w;
            }
          }
          if (do1){
            float4 wa=wq[kb1+kw*64+icb], wb=wq[kb1+kw*64+icb+1];
            #pragma unroll
            for (int j=0;j<4;j++){
              float v=in_[kw+j];
              acc1[0][j]+=v*wa.x; acc1[1][j]+=v*wa.y;
              acc1[2][j]+=v*wa.z; acc1[3][j]+=v*wa.w;
              acc1[4][j]+=v*wb.x; acc1[5][j]+=v*wb.y;
              acc1[6][j]+=v*wb.z; acc1[7][j]+=v*wb.w;
            }
          }
        }
      }
    }
  }
  {
    float* op=r1+((size_t)(d0*HF+y)*8)*WF+x0;
    #pragma unroll
    for (int oc=0;oc<8;oc++){
      float4 o; o.x=fmaxf(acc0[oc][0],0.0f); o.y=fmaxf(acc0[oc][1],0.0f);
      o.z=fmaxf(acc0[oc][2],0.0f); o.w=fmaxf(acc0[oc][3],0.0f);
      *(float4*)(op+(size_t)oc*WF)=o;
    }
  }
  {
    float* op=r1+((size_t)((d0+1)*HF+y)*8)*WF+x0;
    #pragma unroll
    for (int oc=0;oc<8;oc++){
      float4 o; o.x=fmaxf(acc1[oc][0],0.0f); o.y=fmaxf(acc1[oc][1],0.0f);
      o.z=fmaxf(acc1[oc][2],0.0f); o.w=fmaxf(acc1[oc][3],0.0f);
      *(float4*)(op+(size_t)oc*WF)=o;
    }
  }
}

// ---------------- reg2: conv3d 8->1, d-pair per thread, runtime plane loop ----------------
__global__ __launch_bounds__(256) void k_reg2(const float* __restrict__ r1,
    const float* __restrict__ w, const float* __restrict__ bias, float* __restrict__ c2) {
  __shared__ float wl[216]; // raw (1,8,3,3,3): [c][kd][kh][kw]
  int tid=threadIdx.x;
  for (int i=tid;i<216;i+=256) wl[i]=w[i];
  __syncthreads();
  int bid=blockIdx.x;
  int sb=(bid&7)*160+(bid>>3);
  int t=sb*256+tid;
  int x=t%80; int y=(t/80)&63; int dq=t/5120;
  int d0=dq*2;
  float acc0=bias[0], acc1=bias[0];
  for (int pi=0;pi<4;pi++){
    int dd=d0-1+pi; if (dd<0||dd>=DH) continue;
    bool do0=(pi<3), do1=(pi>0);
    for (int kh=0;kh<3;kh++){
      int yy=y-1+kh; if(yy<0||yy>=HF) continue;
      const float* base=r1+((size_t)(dd*HF+yy)*8)*WF+x;
      #pragma unroll
      for (int c=0;c<8;c++){
        const float* rr=base+(size_t)c*WF;
        float in_[3];
        in_[0]=(x>0)?rr[-1]:0.f; in_[1]=rr[0]; in_[2]=(x<79)?rr[1]:0.f;
        #pragma unroll
        for (int kw=0;kw<3;kw++){
          float v=in_[kw];
          if (do0) acc0+=v*wl[((c*3+pi)*3+kh)*3+kw];
          if (do1) acc1+=v*wl[((c*3+pi-1)*3+kh)*3+kw];
        }
      }
    }
  }
  c2[(size_t)d0*NFP+y*WF+x]=acc0;
  c2[(size_t)(d0+1)*NFP+y*WF+x]=acc1;
}

// ---------------- softmax over depth: 32 lanes per pixel ----------------
__global__ __launch_bounds__(256) void k_softmax(const float* __restrict__ c2,
    float* __restrict__ reglow, float* __restrict__ conflow){
  int tid=threadIdx.x;
  int lane=tid&31;
  int p=blockIdx.x*8+(tid>>5);
  const float* cp=c2+p;
  float c[4];
  #pragma unroll
  for (int j=0;j<4;j++) c[j]=cp[(size_t)(lane*4+j)*NFP];
  float m=fmaxf(fmaxf(c[0],c[1]),fmaxf(c[2],c[3]));
  #pragma unroll
  for (int off=1;off<32;off<<=1) m=fmaxf(m,__shfl_xor(m,off));
  float e[4]; float sum=0.f,sumd=0.f;
  #pragma unroll
  for (int j=0;j<4;j++){
    int d=lane*4+j;
    e[j]=expf(c[j]-m);
    sum+=e[j];
    float depth=1.0f/(2.0f-(float)d*(1.8f/127.0f));
    sumd+=e[j]*depth;
  }
  #pragma unroll
  for (int off=1;off<32;off<<=1){ sum+=__shfl_xor(sum,off); sumd+=__shfl_xor(sumd,off); }
  int wl=tid&63;
  float em1=__shfl(e[3],wl-1); if(lane==0) em1=0.f;
  float en0=__shfl(e[0],wl+1); if(lane==31) en0=0.f;
  float en1=__shfl(e[1],wl+1); if(lane==31) en1=0.f;
  float w0=em1 +e[0]+e[1]+e[2];
  float w1=e[0]+e[1]+e[2]+e[3];
  float w2=e[1]+e[2]+e[3]+en0;
  float w3=e[2]+e[3]+en0+en1;
  float mw=fmaxf(fmaxf(w0,w1),fmaxf(w2,w3));
  #pragma unroll
  for (int off=1;off<32;off<<=1) mw=fmaxf(mw,__shfl_xor(mw,off));
  if (lane==0){
    reglow[p]=sumd/sum;
    conflow[p]=mw/sum;
  }
}

// ---------------- x8 bilinear upsample (half-pixel, edge clamp) ----------------
__global__ __launch_bounds__(256) void k_upsample(const float* __restrict__ conflow,
    const float* __restrict__ reglow, float* __restrict__ outconf, float* __restrict__ regup){
  int t=blockIdx.x*256+threadIdx.x;
  int plane=t/NPIX; int p=t%NPIX;
  int oy=p/WIMG, ox=p%WIMG;
  float sy=((float)oy+0.5f)*0.125f-0.5f;
  float sx=((float)ox+0.5f)*0.125f-0.5f;
  float fy=floorf(sy), fx=floorf(sx);
  float wy=sy-fy, wx=sx-fx;
  int y0=(int)fy, x0=(int)fx;
  int y0c=iclamp(y0,0,HF-1), y1c=iclamp(y0+1,0,HF-1);
  int x0c=iclamp(x0,0,WF-1), x1c=iclamp(x0+1,0,WF-1);
  const float* s = plane? reglow : conflow;
  float v = s[y0c*WF+x0c]*(1.0f-wx)*(1.0f-wy)+s[y0c*WF+x1c]*wx*(1.0f-wy)
          + s[y1c*WF+x0c]*(1.0f-wx)*wy + s[y1c*WF+x1c]*wx*wy;
  if (plane==0) outconf[p]=v; else regup[p]=v;
}

// ---------------- fused refinement: conv1(4->32,relu) in LDS, conv2(32->1), add ----------------
__global__ __launch_bounds__(256) void k_refine(const float* __restrict__ img,
    const float* __restrict__ regup,
    const float* __restrict__ w1, const float* __restrict__ b1,
    const float* __restrict__ w2, const float* __restrict__ b2,
    float* __restrict__ outref){
  __shared__ __align__(16) float wl1[1152]; // [tap][ic][oc]
  __shared__ float wl2[288];               // [tap][ic]
  __shared__ float bl1[32];
  __shared__ float hid[32*18*20];          // [oc][hy][hx pad20]
  int tid=threadIdx.x;
  for (int i=tid;i<1152;i+=256){
    int oc=i&31; int rest=i>>5; int ic=rest&3; int tap=rest>>2;
    wl1[i]=w1[(oc*4+ic)*9+tap];
  }
  for (int i=tid;i<288;i+=256){
    int ic=i&31; int tap=i>>5;
    wl2[i]=w2[ic*9+tap];
  }
  if (tid<32) bl1[tid]=b1[tid];
  __syncthreads();
  int bx=blockIdx.x, by=blockIdx.y;
  // phase 1: hidden 18x18 tile (origin -1,-1 rel. to out tile)
  for (int i=tid;i<324;i+=256){
    int hy=i/18, hx=i%18;
    int gy=by*16-1+hy, gx=bx*16-1+hx;
    float a[32];
    if (gy<0||gy>=HIMG||gx<0||gx>=WIMG){
      #pragma unroll
      for (int oc=0;oc<32;oc++) a[oc]=0.0f;
    } else {
      #pragma unroll
      for (int oc=0;oc<32;oc++) a[oc]=bl1[oc];
      #pragma unroll
      for (int ky=0;ky<3;ky++){
        int iy=gy-1+ky; if(iy<0||iy>=HIMG) continue;
        #pragma unroll
        for (int kx=0;kx<3;kx++){
          int ix=gx-1+kx; if(ix<0||ix>=WIMG) continue;
          int tap=ky*3+kx;
          #pragma unroll
          for (int ic=0;ic<4;ic++){
            float v=(ic<3)? img[(size_t)ic*NPIX+(size_t)iy*WIMG+ix]
                          : regup[(size_t)iy*WIMG+ix];
            const float4* wv=(const float4*)&wl1[(tap*4+ic)*32];
            #pragma unroll
            for (int q=0;q<8;q++){
              float4 ww=wv[q];
              a[4*q+0]+=v*ww.x; a[4*q+1]+=v*ww.y;
              a[4*q+2]+=v*ww.z; a[4*q+3]+=v*ww.w;
            }
          }
        }
      }
      #pragma unroll
      for (int oc=0;oc<32;oc++) a[oc]=fmaxf(a[oc],0.0f);
    }
    #pragma unroll
    for (int oc=0;oc<32;oc++) hid[oc*360+hy*20+hx]=a[oc];
  }
  __syncthreads();
  // phase 2: conv2 32->1 from LDS
  int ty=tid>>4, tx=tid&15;
  float acc=b2[0];
  for (int c=0;c<32;c++){
    const float* hb=&hid[c*360];
    #pragma unroll
    for (int ky=0;ky<3;ky++){
      #pragma unroll
      for (int kx=0;kx<3;kx++){
        acc+=hb[(ty+ky)*20+(tx+kx)]*wl2[(ky*3+kx)*32+c];
      }
    }
  }
  int gy=by*16+ty, gx=bx*16+tx;
  size_t p=(size_t)gy*WIMG+gx;
  outref[p]=regup[p]+acc;
}

extern "C" void kernel_launch(void* const* d_in, const int* in_sizes, int n_in,
                              void* d_out, int out_size, void* d_ws, size_t ws_size,
                              hipStream_t stream) {
  (void)in_sizes; (void)n_in; (void)out_size; (void)ws_size;
  const float* images=(const float*)d_in[0];
  const float* Kmat  =(const float*)d_in[1];
  const float* poses =(const float*)d_in[2];
  const float* enc_w1=(const float*)d_in[3];
  const float* enc_b1=(const float*)d_in[4];
  const float* enc_w2=(const float*)d_in[5];
  const float* enc_b2=(const float*)d_in[6];
  const float* enc_w3=(const float*)d_in[7];
  const float* enc_b3=(const float*)d_in[8];
  const float* reg_w1=(const float*)d_in[9];
  const float* reg_b1=(const float*)d_in[10];
  const float* reg_w2=(const float*)d_in[11];
  const float* reg_b2=(const float*)d_in[12];
  const float* ref_w1=(const float*)d_in[13];
  const float* ref_b1=(const float*)d_in[14];
  const float* ref_w2=(const float*)d_in[15];
  const float* ref_b2=(const float*)d_in[16];
  float* ws=(float*)d_ws;
  float* out=(float*)d_out;

  k_setup<<<1,64,0,stream>>>(Kmat,poses,ws+OFF_WP);
  k_conv1<<<1600,256,0,stream>>>(images,enc_w1,enc_b1,ws+OFF_X1);
  k_conv2<<<400,256,0,stream>>>(ws+OFF_X1,enc_w2,enc_b2,ws+OFF_X2);
  k_conv3<<<200,256,0,stream>>>(ws+OFF_X2,enc_w3,enc_b3,ws+OFF_FE);
  k_costvol<<<2560,256,0,stream>>>(ws+OFF_FE,ws+OFF_WP,ws+OFF_COST);
  k_reg1<<<1280,64,0,stream>>>(ws+OFF_COST,reg_w1,reg_b1,ws+OFF_R1);
  k_reg2<<<1280,256,0,stream>>>(ws+OFF_R1,reg_w2,reg_b2,ws+OFF_C2);
  k_softmax<<<640,256,0,stream>>>(ws+OFF_C2,ws+OFF_RL,ws+OFF_CL);
  k_upsample<<<2560,256,0,stream>>>(ws+OFF_CL,ws+OFF_RL,out,ws+OFF_RU);
  k_refine<<<dim3(40,32),256,0,stream>>>(images,ws+OFF_RU,ref_w1,ref_b1,ref_w2,ref_b2,out+NPIX);
}

// Round 7
// 552.117 us; speedup vs baseline: 1.4372x; 1.4372x over previous
//
#include <hip/hip_runtime.h>
#include <math.h>

#define HIMG 512
#define WIMG 640
#define NPIX (HIMG*WIMG)      // 327680
#define HF 64
#define WF 80
#define NFP (HF*WF)           // 5120
#define DH 128
#define CF 32
#define NV 5

// ---- workspace layout (float offsets) ----
#define SZ_X1   (5u*8u*256u*320u)        // 3,276,800
#define SZ_X2   (5u*16u*128u*160u)       // 1,638,400
#define SZ_FE   (5u*NFP*CF)              // 819,200
#define SZ_WP   48u
#define SZ_COST ((unsigned)DH*HF*CF*WF)  // 20,971,520
#define SZ_R1   ((unsigned)DH*HF*8u*WF)  // 5,242,880
#define SZ_C2   ((unsigned)DH*NFP)       // 655,360

#define OFF_X1   0u
#define OFF_X2   (OFF_X1+SZ_X1)
#define OFF_FE   (OFF_X2+SZ_X2)
#define OFF_WP   (OFF_FE+SZ_FE)
#define OFF_COST (OFF_WP+SZ_WP)
#define OFF_R1   (OFF_COST+SZ_COST)
#define OFF_C2   (OFF_R1+SZ_R1)
#define OFF_RL   (OFF_C2+SZ_C2)
#define OFF_CL   (OFF_RL+NFP)
#define OFF_RU   (OFF_CL+NFP)

__device__ __forceinline__ int iclamp(int v, int lo, int hi){ return v<lo?lo:(v>hi?hi:v); }

// ---------------- homography setup (1 thread) ----------------
__global__ void k_setup(const float* __restrict__ Kin, const float* __restrict__ poses,
                        float* __restrict__ warp) {
  if (threadIdx.x != 0 || blockIdx.x != 0) return;
  float Kf[9];
  for (int i=0;i<9;i++) Kf[i]=Kin[i];
  for (int i=0;i<6;i++) Kf[i]*=0.125f;
  float a=Kf[0],b=Kf[1],c=Kf[2],d=Kf[3],e=Kf[4],f=Kf[5],g=Kf[6],h=Kf[7],ii=Kf[8];
  float det=a*(e*ii-f*h)-b*(d*ii-f*g)+c*(d*h-e*g);
  float id=1.0f/det;
  float Ki[9]={(e*ii-f*h)*id,(c*h-b*ii)*id,(b*f-c*e)*id,
               (f*g-d*ii)*id,(a*ii-c*g)*id,(c*d-a*f)*id,
               (d*h-e*g)*id,(b*g-a*h)*id,(a*e-b*d)*id};
  float R0[9]={poses[0],poses[1],poses[2],poses[4],poses[5],poses[6],poses[8],poses[9],poses[10]};
  float t0[3]={poses[3],poses[7],poses[11]};
  for (int v=1; v<NV; v++) {
    const float* P=poses+16*v;
    float Rv[9]={P[0],P[1],P[2],P[4],P[5],P[6],P[8],P[9],P[10]};
    float tv[3]={P[3],P[7],P[11]};
    float TR[9], Tt[3], M[9], A[9], bb[3];
    for (int r=0;r<3;r++)
      for (int cc=0;cc<3;cc++)
        TR[r*3+cc]=Rv[r*3+0]*R0[cc*3+0]+Rv[r*3+1]*R0[cc*3+1]+Rv[r*3+2]*R0[cc*3+2];
    for (int r=0;r<3;r++)
      Tt[r]=tv[r]-(TR[r*3+0]*t0[0]+TR[r*3+1]*t0[1]+TR[r*3+2]*t0[2]);
    for (int r=0;r<3;r++)
      for (int cc=0;cc<3;cc++)
        M[r*3+cc]=TR[r*3+0]*Ki[0*3+cc]+TR[r*3+1]*Ki[1*3+cc]+TR[r*3+2]*Ki[2*3+cc];
    for (int r=0;r<3;r++)
      for (int cc=0;cc<3;cc++)
        A[r*3+cc]=Kf[r*3+0]*M[0*3+cc]+Kf[r*3+1]*M[1*3+cc]+Kf[r*3+2]*M[2*3+cc];
    for (int r=0;r<3;r++)
      bb[r]=Kf[r*3+0]*Tt[0]+Kf[r*3+1]*Tt[1]+Kf[r*3+2]*Tt[2];
    float* o=warp+(v-1)*12;
    for (int i=0;i<9;i++) o[i]=A[i];
    for (int r=0;r<3;r++) o[9+r]=bb[r];
  }
}

// ---------------- encoder conv1: 3->8 stride2, relu ----------------
__global__ __launch_bounds__(256) void k_conv1(const float* __restrict__ img,
    const float* __restrict__ w, const float* __restrict__ bias, float* __restrict__ x1) {
  __shared__ float wl[216];
  int tid=threadIdx.x;
  for (int i=tid;i<216;i+=256){
    int oc=i&7; int rest=i>>3; int kx=rest%3; int ky=(rest/3)%3; int ic=rest/9;
    wl[i]=w[((oc*3+ic)*3+ky)*3+kx];
  }
  __syncthreads();
  int t=blockIdx.x*256+tid;
  int n=t/81920; int r=t%81920; int oy=r/320; int ox=r%320;
  float acc[8];
  #pragma unroll
  for (int oc=0;oc<8;oc++) acc[oc]=bias[oc];
  for (int ic=0;ic<3;ic++){
    const float* ip = img + (n*3+ic)*NPIX;
    #pragma unroll
    for (int ky=0;ky<3;ky++){
      int iy=2*oy+ky; if (iy>=HIMG) continue;
      #pragma unroll
      for (int kx=0;kx<3;kx++){
        int ix=2*ox+kx; if (ix>=WIMG) continue;
        float v=ip[iy*WIMG+ix];
        const float* ww=&wl[((ic*3+ky)*3+kx)*8];
        #pragma unroll
        for (int oc=0;oc<8;oc++) acc[oc]+=v*ww[oc];
      }
    }
  }
  float* op = x1 + (n*8)*81920 + oy*320+ox;
  #pragma unroll
  for (int oc=0;oc<8;oc++){ float vv=fmaxf(acc[oc],0.0f); op[oc*81920]=vv; }
}

// ---------------- encoder conv2: 8->16 stride2, relu ----------------
__global__ __launch_bounds__(256) void k_conv2(const float* __restrict__ x1,
    const float* __restrict__ w, const float* __restrict__ bias, float* __restrict__ x2){
  __shared__ float wl[1152];
  int tid=threadIdx.x;
  for (int i=tid;i<1152;i+=256){
    int oc=i&15; int rest=i>>4; int tap=rest%9; int ic=rest/9;
    int ky=tap/3, kx=tap%3;
    wl[i]=w[((oc*8+ic)*3+ky)*3+kx];
  }
  __syncthreads();
  int t=blockIdx.x*256+tid;
  int n=t/20480; int r=t%20480; int oy=r/160; int ox=r%160;
  float acc[16];
  #pragma unroll
  for (int oc=0;oc<16;oc++) acc[oc]=bias[oc];
  for (int ic=0;ic<8;ic++){
    const float* ip=x1+(n*8+ic)*81920;
    #pragma unroll
    for (int ky=0;ky<3;ky++){
      int iy=2*oy+ky; if(iy>=256) continue;
      #pragma unroll
      for (int kx=0;kx<3;kx++){
        int ix=2*ox+kx; if(ix>=320) continue;
        float v=ip[iy*320+ix];
        const float* ww=&wl[(ic*9+ky*3+kx)*16];
        #pragma unroll
        for (int oc=0;oc<16;oc++) acc[oc]+=v*ww[oc];
      }
    }
  }
  float* op=x2+(n*16)*20480+oy*160+ox;
  #pragma unroll
  for (int oc=0;oc<16;oc++){ float vv=fmaxf(acc[oc],0.0f); op[oc*20480]=vv; }
}

// ---------------- encoder conv3: 16->32 stride2, oc-split x2, channel-last out ----------------
__global__ __launch_bounds__(256) void k_conv3(const float* __restrict__ x2,
    const float* __restrict__ w, const float* __restrict__ bias, float* __restrict__ fe){
  __shared__ float wl[4608];
  int tid=threadIdx.x;
  for (int i=tid;i<4608;i+=256){
    int oc=i&31; int rest=i>>5; int tap=rest%9; int ic=rest/9;
    int ky=tap/3,kx=tap%3;
    wl[i]=w[((oc*16+ic)*3+ky)*3+kx];
  }
  __syncthreads();
  int t=blockIdx.x*256+tid;          // 51200
  int half=t&1; int r=t>>1;          // r: 0..25599
  int n=r/NFP; int p=r%NFP; int oy=p/WF; int ox=p%WF;
  float acc[16];
  #pragma unroll
  for (int oc=0;oc<16;oc++) acc[oc]=bias[half*16+oc];
  for (int ic=0;ic<16;ic++){
    const float* ip=x2+(n*16+ic)*20480;
    #pragma unroll
    for (int ky=0;ky<3;ky++){
      int iy=2*oy+ky; if(iy>=128) continue;
      #pragma unroll
      for (int kx=0;kx<3;kx++){
        int ix=2*ox+kx; if(ix>=160) continue;
        float v=ip[iy*160+ix];
        const float* ww=&wl[(ic*9+ky*3+kx)*32+half*16];
        #pragma unroll
        for (int oc=0;oc<16;oc++) acc[oc]+=v*ww[oc];
      }
    }
  }
  float* op=fe+(size_t)r*CF+half*16;
  #pragma unroll
  for (int q=0;q<4;q++) ((float4*)op)[q]=((float4*)acc)[q];
}

// ---------------- plane-sweep cost volume, channel-major gathers ----------------
// One block per (d,y) row. Phase A: 80 threads compute per-px homography params
// (validity-masked weights + pre-clamped corner offsets) into LDS. Phase B:
// 32c x 8px lanes -> every corner gather is a 128B contiguous load.
// out layout: cost[((d*HF+y)*CF + c)*WF + x]
__global__ __launch_bounds__(256) void k_costvol(const float* __restrict__ fe,
    const float* __restrict__ warp, float* __restrict__ cost){
  __shared__ float pw[80][4][4];   // [px][view-1][w00,w01,w10,w11]
  __shared__ int   po[80][4][4];   // [px][view-1][corner px-offset]
  __shared__ float otile[32][81];  // pad 81: conflict-free transpose
  int bid=blockIdx.x;              // 0..8191 = d*64+y
  int d=bid>>6; int y=bid&63;
  int tid=threadIdx.x;
  float invd=2.0f-(float)d*(1.8f/127.0f);
  float depth=1.0f/invd;
  if (tid<80){
    int x=tid;
    float fx=(float)x, fy=(float)y;
    for (int v=1; v<NV; v++){
      const float* W=warp+(v-1)*12;
      float u_=depth*(W[0]*fx+W[1]*fy+W[2])+W[9];
      float v_=depth*(W[3]*fx+W[4]*fy+W[5])+W[10];
      float z_=depth*(W[6]*fx+W[7]*fy+W[8])+W[11];
      float valid=(z_>0.001f)?1.0f:0.0f;
      float zc=(z_>0.001f)?z_:0.001f;
      float uu=u_/zc, vv=v_/zc;
      float fx0=floorf(uu), fy0=floorf(vv);
      float wx=uu-fx0, wy=vv-fy0;
      int xi=(int)fx0, yi=(int)fy0;
      float m00=((xi>=0)&&(xi<WF)&&(yi>=0)&&(yi<HF))?valid:0.0f;
      float m01=((xi+1>=0)&&(xi+1<WF)&&(yi>=0)&&(yi<HF))?valid:0.0f;
      float m10=((xi>=0)&&(xi<WF)&&(yi+1>=0)&&(yi+1<HF))?valid:0.0f;
      float m11=((xi+1>=0)&&(xi+1<WF)&&(yi+1>=0)&&(yi+1<HF))?valid:0.0f;
      pw[x][v-1][0]=(1.0f-wx)*(1.0f-wy)*m00;
      pw[x][v-1][1]=wx*(1.0f-wy)*m01;
      pw[x][v-1][2]=(1.0f-wx)*wy*m10;
      pw[x][v-1][3]=wx*wy*m11;
      int xc0=iclamp(xi,0,WF-1), xc1=iclamp(xi+1,0,WF-1);
      int yc0=iclamp(yi,0,HF-1), yc1=iclamp(yi+1,0,HF-1);
      po[x][v-1][0]=yc0*WF+xc0;
      po[x][v-1][1]=yc0*WF+xc1;
      po[x][v-1][2]=yc1*WF+xc0;
      po[x][v-1][3]=yc1*WF+xc1;
    }
  }
  __syncthreads();
  int c=tid&31, slot=tid>>5;
  float s[10], ss[10];
  #pragma unroll
  for (int i=0;i<10;i++){
    int px=i*8+slot;
    float r=fe[(size_t)(y*WF+px)*CF+c];
    s[i]=r; ss[i]=r*r;
  }
  for (int v=1; v<NV; v++){
    const float* fb=fe+(size_t)v*NFP*CF;
    #pragma unroll
    for (int i=0;i<10;i++){
      int px=i*8+slot;
      float w0=pw[px][v-1][0], w1=pw[px][v-1][1];
      float w2=pw[px][v-1][2], w3=pw[px][v-1][3];
      int o0=po[px][v-1][0], o1=po[px][v-1][1];
      int o2=po[px][v-1][2], o3=po[px][v-1][3];
      float a=fb[(size_t)o0*CF+c];
      float b=fb[(size_t)o1*CF+c];
      float g=fb[(size_t)o2*CF+c];
      float h=fb[(size_t)o3*CF+c];
      float val=w0*a+w1*b+w2*g+w3*h;
      s[i]+=val; ss[i]+=val*val;
    }
  }
  #pragma unroll
  for (int i=0;i<10;i++){
    int px=i*8+slot;
    float mean=s[i]*0.2f;
    otile[c][px]=ss[i]*0.2f-mean*mean;
  }
  __syncthreads();
  float* cp=cost+(size_t)(d*HF+y)*CF*WF;
  for (int i=tid;i<2560;i+=256){
    int cc=i/80, px=i%80;
    cp[i]=otile[cc][px];
  }
}

// ---------------- reg1: conv3d 32->8 + relu; out (d,y,oc,x) ----------------
// Round-2 config (empirical best): 1280 blocks x 256 thr, 8oc x 2x per thread,
// XCD d-swizzle, no d-pair. 188us known-good; d-pair variants all lost to latency.
__global__ __launch_bounds__(256) void k_reg1(const float* __restrict__ cost,
    const float* __restrict__ w, const float* __restrict__ bias, float* __restrict__ r1) {
  __shared__ __align__(16) float wl[6912]; // [tap][ic][oc]
  int tid=threadIdx.x;
  for (int i=tid;i<6912;i+=256){
    int oc=i&7; int ic=(i>>3)&31; int tap=i>>8;
    int kd=tap/9; int rem=tap%9; int kh=rem/3; int kw=rem%3;
    wl[i]=w[(((oc*32+ic)*3+kd)*3+kh)*3+kw];
  }
  __syncthreads();
  int bid=blockIdx.x;
  int sb=(bid&7)*160 + (bid>>3);
  int t=sb*256+tid;
  int xp=t%40; int y=(t/40)&63; int d=t/2560;
  int x0=xp*2;
  float acc[8][2];
  #pragma unroll
  for (int oc=0;oc<8;oc++){
    float bb=bias[oc];
    acc[oc][0]=bb; acc[oc][1]=bb;
  }
  const float4* wq=(const float4*)wl;
  for (int kd=0;kd<3;kd++){
    int dd=d-1+kd; if (dd<0||dd>=DH) continue;
    for (int kh=0;kh<3;kh++){
      int yy=y-1+kh; if (yy<0||yy>=HF) continue;
      const float* base = cost + ((size_t)(dd*HF+yy)*CF)*WF + x0;
      int tb0=((kd*3+kh)*3)*64;
      for (int ic=0;ic<CF;ic++){
        const float* rr = base + (size_t)ic*WF;
        float in_[4];
        in_[0] = (x0>0)? rr[-1] : 0.0f;
        in_[1] = rr[0];
        in_[2] = rr[1];
        in_[3] = (x0<78)? rr[2] : 0.0f;
        #pragma unroll
        for (int kw=0;kw<3;kw++){
          float4 wa=wq[tb0+kw*64+ic*2];
          float4 wb=wq[tb0+kw*64+ic*2+1];
          float w8[8]={wa.x,wa.y,wa.z,wa.w,wb.x,wb.y,wb.z,wb.w};
          float v0=in_[kw], v1=in_[kw+1];
          #pragma unroll
          for (int oc=0;oc<8;oc++){
            acc[oc][0]+=v0*w8[oc];
            acc[oc][1]+=v1*w8[oc];
          }
        }
      }
    }
  }
  float* op = r1 + ((size_t)(d*HF+y)*8)*WF + x0;
  #pragma unroll
  for (int oc=0;oc<8;oc++){
    float2 o;
    o.x=fmaxf(acc[oc][0],0.0f);
    o.y=fmaxf(acc[oc][1],0.0f);
    *(float2*)(op+(size_t)oc*WF)=o;
  }
}

// ---------------- reg2: conv3d 8->1, d-pair per thread, runtime plane loop ----------------
__global__ __launch_bounds__(256) void k_reg2(const float* __restrict__ r1,
    const float* __restrict__ w, const float* __restrict__ bias, float* __restrict__ c2) {
  __shared__ float wl[216]; // raw (1,8,3,3,3): [c][kd][kh][kw]
  int tid=threadIdx.x;
  for (int i=tid;i<216;i+=256) wl[i]=w[i];
  __syncthreads();
  int bid=blockIdx.x;
  int sb=(bid&7)*160+(bid>>3);
  int t=sb*256+tid;
  int x=t%80; int y=(t/80)&63; int dq=t/5120;
  int d0=dq*2;
  float acc0=bias[0], acc1=bias[0];
  for (int pi=0;pi<4;pi++){
    int dd=d0-1+pi; if (dd<0||dd>=DH) continue;
    bool do0=(pi<3), do1=(pi>0);
    for (int kh=0;kh<3;kh++){
      int yy=y-1+kh; if(yy<0||yy>=HF) continue;
      const float* base=r1+((size_t)(dd*HF+yy)*8)*WF+x;
      #pragma unroll
      for (int c=0;c<8;c++){
        const float* rr=base+(size_t)c*WF;
        float in_[3];
        in_[0]=(x>0)?rr[-1]:0.f; in_[1]=rr[0]; in_[2]=(x<79)?rr[1]:0.f;
        #pragma unroll
        for (int kw=0;kw<3;kw++){
          float v=in_[kw];
          if (do0) acc0+=v*wl[((c*3+pi)*3+kh)*3+kw];
          if (do1) acc1+=v*wl[((c*3+pi-1)*3+kh)*3+kw];
        }
      }
    }
  }
  c2[(size_t)d0*NFP+y*WF+x]=acc0;
  c2[(size_t)(d0+1)*NFP+y*WF+x]=acc1;
}

// ---------------- softmax over depth: 32 lanes per pixel ----------------
__global__ __launch_bounds__(256) void k_softmax(const float* __restrict__ c2,
    float* __restrict__ reglow, float* __restrict__ conflow){
  int tid=threadIdx.x;
  int lane=tid&31;
  int p=blockIdx.x*8+(tid>>5);
  const float* cp=c2+p;
  float c[4];
  #pragma unroll
  for (int j=0;j<4;j++) c[j]=cp[(size_t)(lane*4+j)*NFP];
  float m=fmaxf(fmaxf(c[0],c[1]),fmaxf(c[2],c[3]));
  #pragma unroll
  for (int off=1;off<32;off<<=1) m=fmaxf(m,__shfl_xor(m,off));
  float e[4]; float sum=0.f,sumd=0.f;
  #pragma unroll
  for (int j=0;j<4;j++){
    int d=lane*4+j;
    e[j]=expf(c[j]-m);
    sum+=e[j];
    float depth=1.0f/(2.0f-(float)d*(1.8f/127.0f));
    sumd+=e[j]*depth;
  }
  #pragma unroll
  for (int off=1;off<32;off<<=1){ sum+=__shfl_xor(sum,off); sumd+=__shfl_xor(sumd,off); }
  int wl=tid&63;
  float em1=__shfl(e[3],wl-1); if(lane==0) em1=0.f;
  float en0=__shfl(e[0],wl+1); if(lane==31) en0=0.f;
  float en1=__shfl(e[1],wl+1); if(lane==31) en1=0.f;
  float w0=em1 +e[0]+e[1]+e[2];
  float w1=e[0]+e[1]+e[2]+e[3];
  float w2=e[1]+e[2]+e[3]+en0;
  float w3=e[2]+e[3]+en0+en1;
  float mw=fmaxf(fmaxf(w0,w1),fmaxf(w2,w3));
  #pragma unroll
  for (int off=1;off<32;off<<=1) mw=fmaxf(mw,__shfl_xor(mw,off));
  if (lane==0){
    reglow[p]=sumd/sum;
    conflow[p]=mw/sum;
  }
}

// ---------------- x8 bilinear upsample (half-pixel, edge clamp) ----------------
__global__ __launch_bounds__(256) void k_upsample(const float* __restrict__ conflow,
    const float* __restrict__ reglow, float* __restrict__ outconf, float* __restrict__ regup){
  int t=blockIdx.x*256+threadIdx.x;
  int plane=t/NPIX; int p=t%NPIX;
  int oy=p/WIMG, ox=p%WIMG;
  float sy=((float)oy+0.5f)*0.125f-0.5f;
  float sx=((float)ox+0.5f)*0.125f-0.5f;
  float fy=floorf(sy), fx=floorf(sx);
  float wy=sy-fy, wx=sx-fx;
  int y0=(int)fy, x0=(int)fx;
  int y0c=iclamp(y0,0,HF-1), y1c=iclamp(y0+1,0,HF-1);
  int x0c=iclamp(x0,0,WF-1), x1c=iclamp(x0+1,0,WF-1);
  const float* s = plane? reglow : conflow;
  float v = s[y0c*WF+x0c]*(1.0f-wx)*(1.0f-wy)+s[y0c*WF+x1c]*wx*(1.0f-wy)
          + s[y1c*WF+x0c]*(1.0f-wx)*wy + s[y1c*WF+x1c]*wx*wy;
  if (plane==0) outconf[p]=v; else regup[p]=v;
}

// ---------------- fused refinement: conv1(4->32,relu) in LDS, conv2(32->1), add ----------------
__global__ __launch_bounds__(256) void k_refine(const float* __restrict__ img,
    const float* __restrict__ regup,
    const float* __restrict__ w1, const float* __restrict__ b1,
    const float* __restrict__ w2, const float* __restrict__ b2,
    float* __restrict__ outref){
  __shared__ __align__(16) float wl1[1152]; // [tap][ic][oc]
  __shared__ float wl2[288];               // [tap][ic]
  __shared__ float bl1[32];
  __shared__ float hid[32*18*20];          // [oc][hy][hx pad20]
  int tid=threadIdx.x;
  for (int i=tid;i<1152;i+=256){
    int oc=i&31; int rest=i>>5; int ic=rest&3; int tap=rest>>2;
    wl1[i]=w1[(oc*4+ic)*9+tap];
  }
  for (int i=tid;i<288;i+=256){
    int ic=i&31; int tap=i>>5;
    wl2[i]=w2[ic*9+tap];
  }
  if (tid<32) bl1[tid]=b1[tid];
  __syncthreads();
  int bx=blockIdx.x, by=blockIdx.y;
  // phase 1: hidden 18x18 tile (origin -1,-1 rel. to out tile)
  for (int i=tid;i<324;i+=256){
    int hy=i/18, hx=i%18;
    int gy=by*16-1+hy, gx=bx*16-1+hx;
    float a[32];
    if (gy<0||gy>=HIMG||gx<0||gx>=WIMG){
      #pragma unroll
      for (int oc=0;oc<32;oc++) a[oc]=0.0f;
    } else {
      #pragma unroll
      for (int oc=0;oc<32;oc++) a[oc]=bl1[oc];
      #pragma unroll
      for (int ky=0;ky<3;ky++){
        int iy=gy-1+ky; if(iy<0||iy>=HIMG) continue;
        #pragma unroll
        for (int kx=0;kx<3;kx++){
          int ix=gx-1+kx; if(ix<0||ix>=WIMG) continue;
          int tap=ky*3+kx;
          #pragma unroll
          for (int ic=0;ic<4;ic++){
            float v=(ic<3)? img[(size_t)ic*NPIX+(size_t)iy*WIMG+ix]
                          : regup[(size_t)iy*WIMG+ix];
            const float4* wv=(const float4*)&wl1[(tap*4+ic)*32];
            #pragma unroll
            for (int q=0;q<8;q++){
              float4 ww=wv[q];
              a[4*q+0]+=v*ww.x; a[4*q+1]+=v*ww.y;
              a[4*q+2]+=v*ww.z; a[4*q+3]+=v*ww.w;
            }
          }
        }
      }
      #pragma unroll
      for (int oc=0;oc<32;oc++) a[oc]=fmaxf(a[oc],0.0f);
    }
    #pragma unroll
    for (int oc=0;oc<32;oc++) hid[oc*360+hy*20+hx]=a[oc];
  }
  __syncthreads();
  // phase 2: conv2 32->1 from LDS
  int ty=tid>>4, tx=tid&15;
  float acc=b2[0];
  for (int c=0;c<32;c++){
    const float* hb=&hid[c*360];
    #pragma unroll
    for (int ky=0;ky<3;ky++){
      #pragma unroll
      for (int kx=0;kx<3;kx++){
        acc+=hb[(ty+ky)*20+(tx+kx)]*wl2[(ky*3+kx)*32+c];
      }
    }
  }
  int gy=by*16+ty, gx=bx*16+tx;
  size_t p=(size_t)gy*WIMG+gx;
  outref[p]=regup[p]+acc;
}

extern "C" void kernel_launch(void* const* d_in, const int* in_sizes, int n_in,
                              void* d_out, int out_size, void* d_ws, size_t ws_size,
                              hipStream_t stream) {
  (void)in_sizes; (void)n_in; (void)out_size; (void)ws_size;
  const float* images=(const float*)d_in[0];
  const float* Kmat  =(const float*)d_in[1];
  const float* poses =(const float*)d_in[2];
  const float* enc_w1=(const float*)d_in[3];
  const float* enc_b1=(const float*)d_in[4];
  const float* enc_w2=(const float*)d_in[5];
  const float* enc_b2=(const float*)d_in[6];
  const float* enc_w3=(const float*)d_in[7];
  const float* enc_b3=(const float*)d_in[8];
  const float* reg_w1=(const float*)d_in[9];
  const float* reg_b1=(const float*)d_in[10];
  const float* reg_w2=(const float*)d_in[11];
  const float* reg_b2=(const float*)d_in[12];
  const float* ref_w1=(const float*)d_in[13];
  const float* ref_b1=(const float*)d_in[14];
  const float* ref_w2=(const float*)d_in[15];
  const float* ref_b2=(const float*)d_in[16];
  float* ws=(float*)d_ws;
  float* out=(float*)d_out;

  k_setup<<<1,64,0,stream>>>(Kmat,poses,ws+OFF_WP);
  k_conv1<<<1600,256,0,stream>>>(images,enc_w1,enc_b1,ws+OFF_X1);
  k_conv2<<<400,256,0,stream>>>(ws+OFF_X1,enc_w2,enc_b2,ws+OFF_X2);
  k_conv3<<<200,256,0,stream>>>(ws+OFF_X2,enc_w3,enc_b3,ws+OFF_FE);
  k_costvol<<<8192,256,0,stream>>>(ws+OFF_FE,ws+OFF_WP,ws+OFF_COST);
  k_reg1<<<1280,256,0,stream>>>(ws+OFF_COST,reg_w1,reg_b1,ws+OFF_R1);
  k_reg2<<<1280,256,0,stream>>>(ws+OFF_R1,reg_w2,reg_b2,ws+OFF_C2);
  k_softmax<<<640,256,0,stream>>>(ws+OFF_C2,ws+OFF_RL,ws+OFF_CL);
  k_upsample<<<2560,256,0,stream>>>(ws+OFF_CL,ws+OFF_RL,out,ws+OFF_RU);
  k_refine<<<dim3(40,32),256,0,stream>>>(images,ws+OFF_RU,ref_w1,ref_b1,ref_w2,ref_b2,out+NPIX);
}

// Round 8
// 463.652 us; speedup vs baseline: 1.7115x; 1.1908x over previous
//
#include <hip/hip_runtime.h>
#include <math.h>

#define HIMG 512
#define WIMG 640
#define NPIX (HIMG*WIMG)      // 327680
#define HF 64
#define WF 80
#define NFP (HF*WF)           // 5120
#define DH 128
#define CF 32
#define NV 5

// ---- workspace layout (float offsets) ----
#define SZ_X1   (5u*8u*256u*320u)        // 3,276,800
#define SZ_X2   (5u*16u*128u*160u)       // 1,638,400
#define SZ_FE   (5u*NFP*CF)              // 819,200
#define SZ_WP   48u
#define SZ_COST ((unsigned)DH*HF*CF*WF)  // 20,971,520 elements (stored as bf16: half the floats)
#define SZ_R1   ((unsigned)DH*HF*8u*WF)  // 5,242,880
#define SZ_C2   ((unsigned)DH*NFP)       // 655,360

#define OFF_X1   0u
#define OFF_X2   (OFF_X1+SZ_X1)
#define OFF_FE   (OFF_X2+SZ_X2)
#define OFF_WP   (OFF_FE+SZ_FE)
#define OFF_COST (OFF_WP+SZ_WP)
#define OFF_R1   (OFF_COST+SZ_COST)
#define OFF_C2   (OFF_R1+SZ_R1)
#define OFF_RL   (OFF_C2+SZ_C2)
#define OFF_CL   (OFF_RL+NFP)
#define OFF_RU   (OFF_CL+NFP)
#define OFF_WB   (OFF_RU+NPIX)   // bf16 B-fragments for reg1 MFMA (27 taps x 1KB)

typedef __attribute__((ext_vector_type(8))) short bf16x8;
typedef __attribute__((ext_vector_type(4))) float f32x4;

__device__ __forceinline__ int iclamp(int v, int lo, int hi){ return v<lo?lo:(v>hi?hi:v); }

__device__ __forceinline__ unsigned short f2bf(float f){
  union { float f; unsigned u; } v; v.f=f;
  unsigned r=v.u+0x7fffu+((v.u>>16)&1u);
  return (unsigned short)(r>>16);
}

// ---------------- homography setup (1 thread) ----------------
__global__ void k_setup(const float* __restrict__ Kin, const float* __restrict__ poses,
                        float* __restrict__ warp) {
  if (threadIdx.x != 0 || blockIdx.x != 0) return;
  float Kf[9];
  for (int i=0;i<9;i++) Kf[i]=Kin[i];
  for (int i=0;i<6;i++) Kf[i]*=0.125f;
  float a=Kf[0],b=Kf[1],c=Kf[2],d=Kf[3],e=Kf[4],f=Kf[5],g=Kf[6],h=Kf[7],ii=Kf[8];
  float det=a*(e*ii-f*h)-b*(d*ii-f*g)+c*(d*h-e*g);
  float id=1.0f/det;
  float Ki[9]={(e*ii-f*h)*id,(c*h-b*ii)*id,(b*f-c*e)*id,
               (f*g-d*ii)*id,(a*ii-c*g)*id,(c*d-a*f)*id,
               (d*h-e*g)*id,(b*g-a*h)*id,(a*e-b*d)*id};
  float R0[9]={poses[0],poses[1],poses[2],poses[4],poses[5],poses[6],poses[8],poses[9],poses[10]};
  float t0[3]={poses[3],poses[7],poses[11]};
  for (int v=1; v<NV; v++) {
    const float* P=poses+16*v;
    float Rv[9]={P[0],P[1],P[2],P[4],P[5],P[6],P[8],P[9],P[10]};
    float tv[3]={P[3],P[7],P[11]};
    float TR[9], Tt[3], M[9], A[9], bb[3];
    for (int r=0;r<3;r++)
      for (int cc=0;cc<3;cc++)
        TR[r*3+cc]=Rv[r*3+0]*R0[cc*3+0]+Rv[r*3+1]*R0[cc*3+1]+Rv[r*3+2]*R0[cc*3+2];
    for (int r=0;r<3;r++)
      Tt[r]=tv[r]-(TR[r*3+0]*t0[0]+TR[r*3+1]*t0[1]+TR[r*3+2]*t0[2]);
    for (int r=0;r<3;r++)
      for (int cc=0;cc<3;cc++)
        M[r*3+cc]=TR[r*3+0]*Ki[0*3+cc]+TR[r*3+1]*Ki[1*3+cc]+TR[r*3+2]*Ki[2*3+cc];
    for (int r=0;r<3;r++)
      for (int cc=0;cc<3;cc++)
        A[r*3+cc]=Kf[r*3+0]*M[0*3+cc]+Kf[r*3+1]*M[1*3+cc]+Kf[r*3+2]*M[2*3+cc];
    for (int r=0;r<3;r++)
      bb[r]=Kf[r*3+0]*Tt[0]+Kf[r*3+1]*Tt[1]+Kf[r*3+2]*Tt[2];
    float* o=warp+(v-1)*12;
    for (int i=0;i<9;i++) o[i]=A[i];
    for (int r=0;r<3;r++) o[9+r]=bb[r];
  }
}

// ---------------- pack reg1 weights into bf16 B-fragments ----------------
// wb[tap*512 + lane*8 + j] : B[k=ic][n=oc], k=(lane>>4)*8+j, n=lane&15 (oc<8 real, else 0)
__global__ void k_wprep(const float* __restrict__ w, unsigned short* __restrict__ wb){
  int tid=blockIdx.x*256+threadIdx.x;
  for (int idx=tid; idx<13824; idx+=256){
    int tap=idx>>9; int r=idx&511;
    int lane=r>>3; int j=r&7;
    int n=lane&15; int k=(lane>>4)*8+j;
    int kd=tap/9; int kh=(tap/3)%3; int kw=tap%3;
    float val=(n<8)? w[(((n*32+k)*3+kd)*3+kh)*3+kw] : 0.0f;
    wb[idx]=f2bf(val);
  }
}

// ---------------- encoder conv1: 3->8 stride2, relu ----------------
__global__ __launch_bounds__(256) void k_conv1(const float* __restrict__ img,
    const float* __restrict__ w, const float* __restrict__ bias, float* __restrict__ x1) {
  __shared__ float wl[216];
  int tid=threadIdx.x;
  for (int i=tid;i<216;i+=256){
    int oc=i&7; int rest=i>>3; int kx=rest%3; int ky=(rest/3)%3; int ic=rest/9;
    wl[i]=w[((oc*3+ic)*3+ky)*3+kx];
  }
  __syncthreads();
  int t=blockIdx.x*256+tid;
  int n=t/81920; int r=t%81920; int oy=r/320; int ox=r%320;
  float acc[8];
  #pragma unroll
  for (int oc=0;oc<8;oc++) acc[oc]=bias[oc];
  for (int ic=0;ic<3;ic++){
    const float* ip = img + (n*3+ic)*NPIX;
    #pragma unroll
    for (int ky=0;ky<3;ky++){
      int iy=2*oy+ky; if (iy>=HIMG) continue;
      #pragma unroll
      for (int kx=0;kx<3;kx++){
        int ix=2*ox+kx; if (ix>=WIMG) continue;
        float v=ip[iy*WIMG+ix];
        const float* ww=&wl[((ic*3+ky)*3+kx)*8];
        #pragma unroll
        for (int oc=0;oc<8;oc++) acc[oc]+=v*ww[oc];
      }
    }
  }
  float* op = x1 + (n*8)*81920 + oy*320+ox;
  #pragma unroll
  for (int oc=0;oc<8;oc++){ float vv=fmaxf(acc[oc],0.0f); op[oc*81920]=vv; }
}

// ---------------- encoder conv2: 8->16 stride2, relu ----------------
__global__ __launch_bounds__(256) void k_conv2(const float* __restrict__ x1,
    const float* __restrict__ w, const float* __restrict__ bias, float* __restrict__ x2){
  __shared__ float wl[1152];
  int tid=threadIdx.x;
  for (int i=tid;i<1152;i+=256){
    int oc=i&15; int rest=i>>4; int tap=rest%9; int ic=rest/9;
    int ky=tap/3, kx=tap%3;
    wl[i]=w[((oc*8+ic)*3+ky)*3+kx];
  }
  __syncthreads();
  int t=blockIdx.x*256+tid;
  int n=t/20480; int r=t%20480; int oy=r/160; int ox=r%160;
  float acc[16];
  #pragma unroll
  for (int oc=0;oc<16;oc++) acc[oc]=bias[oc];
  for (int ic=0;ic<8;ic++){
    const float* ip=x1+(n*8+ic)*81920;
    #pragma unroll
    for (int ky=0;ky<3;ky++){
      int iy=2*oy+ky; if(iy>=256) continue;
      #pragma unroll
      for (int kx=0;kx<3;kx++){
        int ix=2*ox+kx; if(ix>=320) continue;
        float v=ip[iy*320+ix];
        const float* ww=&wl[(ic*9+ky*3+kx)*16];
        #pragma unroll
        for (int oc=0;oc<16;oc++) acc[oc]+=v*ww[oc];
      }
    }
  }
  float* op=x2+(n*16)*20480+oy*160+ox;
  #pragma unroll
  for (int oc=0;oc<16;oc++){ float vv=fmaxf(acc[oc],0.0f); op[oc*20480]=vv; }
}

// ---------------- encoder conv3: 16->32 stride2, oc-split x2, channel-last out ----------------
__global__ __launch_bounds__(256) void k_conv3(const float* __restrict__ x2,
    const float* __restrict__ w, const float* __restrict__ bias, float* __restrict__ fe){
  __shared__ float wl[4608];
  int tid=threadIdx.x;
  for (int i=tid;i<4608;i+=256){
    int oc=i&31; int rest=i>>5; int tap=rest%9; int ic=rest/9;
    int ky=tap/3,kx=tap%3;
    wl[i]=w[((oc*16+ic)*3+ky)*3+kx];
  }
  __syncthreads();
  int t=blockIdx.x*256+tid;          // 51200
  int half=t&1; int r=t>>1;          // r: 0..25599
  int n=r/NFP; int p=r%NFP; int oy=p/WF; int ox=p%WF;
  float acc[16];
  #pragma unroll
  for (int oc=0;oc<16;oc++) acc[oc]=bias[half*16+oc];
  for (int ic=0;ic<16;ic++){
    const float* ip=x2+(n*16+ic)*20480;
    #pragma unroll
    for (int ky=0;ky<3;ky++){
      int iy=2*oy+ky; if(iy>=128) continue;
      #pragma unroll
      for (int kx=0;kx<3;kx++){
        int ix=2*ox+kx; if(ix>=160) continue;
        float v=ip[iy*160+ix];
        const float* ww=&wl[(ic*9+ky*3+kx)*32+half*16];
        #pragma unroll
        for (int oc=0;oc<16;oc++) acc[oc]+=v*ww[oc];
      }
    }
  }
  float* op=fe+(size_t)r*CF+half*16;
  #pragma unroll
  for (int q=0;q<4;q++) ((float4*)op)[q]=((float4*)acc)[q];
}

// ---------------- plane-sweep cost volume, channel-major gathers, bf16 (d,y,x,ic) out ----------------
__global__ __launch_bounds__(256) void k_costvol(const float* __restrict__ fe,
    const float* __restrict__ warp, unsigned short* __restrict__ costb){
  __shared__ float pw[80][4][4];   // [px][view-1][w00,w01,w10,w11]
  __shared__ int   po[80][4][4];   // [px][view-1][corner px-offset]
  int bid=blockIdx.x;              // 0..8191 = d*64+y
  int d=bid>>6; int y=bid&63;
  int tid=threadIdx.x;
  float invd=2.0f-(float)d*(1.8f/127.0f);
  float depth=1.0f/invd;
  if (tid<80){
    int x=tid;
    float fx=(float)x, fy=(float)y;
    for (int v=1; v<NV; v++){
      const float* W=warp+(v-1)*12;
      float u_=depth*(W[0]*fx+W[1]*fy+W[2])+W[9];
      float v_=depth*(W[3]*fx+W[4]*fy+W[5])+W[10];
      float z_=depth*(W[6]*fx+W[7]*fy+W[8])+W[11];
      float valid=(z_>0.001f)?1.0f:0.0f;
      float zc=(z_>0.001f)?z_:0.001f;
      float uu=u_/zc, vv=v_/zc;
      float fx0=floorf(uu), fy0=floorf(vv);
      float wx=uu-fx0, wy=vv-fy0;
      int xi=(int)fx0, yi=(int)fy0;
      float m00=((xi>=0)&&(xi<WF)&&(yi>=0)&&(yi<HF))?valid:0.0f;
      float m01=((xi+1>=0)&&(xi+1<WF)&&(yi>=0)&&(yi<HF))?valid:0.0f;
      float m10=((xi>=0)&&(xi<WF)&&(yi+1>=0)&&(yi+1<HF))?valid:0.0f;
      float m11=((xi+1>=0)&&(xi+1<WF)&&(yi+1>=0)&&(yi+1<HF))?valid:0.0f;
      pw[x][v-1][0]=(1.0f-wx)*(1.0f-wy)*m00;
      pw[x][v-1][1]=wx*(1.0f-wy)*m01;
      pw[x][v-1][2]=(1.0f-wx)*wy*m10;
      pw[x][v-1][3]=wx*wy*m11;
      int xc0=iclamp(xi,0,WF-1), xc1=iclamp(xi+1,0,WF-1);
      int yc0=iclamp(yi,0,HF-1), yc1=iclamp(yi+1,0,HF-1);
      po[x][v-1][0]=yc0*WF+xc0;
      po[x][v-1][1]=yc0*WF+xc1;
      po[x][v-1][2]=yc1*WF+xc0;
      po[x][v-1][3]=yc1*WF+xc1;
    }
  }
  __syncthreads();
  int c=tid&31, slot=tid>>5;
  float s[10], ss[10];
  #pragma unroll
  for (int i=0;i<10;i++){
    int px=i*8+slot;
    float r=fe[(size_t)(y*WF+px)*CF+c];
    s[i]=r; ss[i]=r*r;
  }
  for (int v=1; v<NV; v++){
    const float* fb=fe+(size_t)v*NFP*CF;
    #pragma unroll
    for (int i=0;i<10;i++){
      int px=i*8+slot;
      float w0=pw[px][v-1][0], w1=pw[px][v-1][1];
      float w2=pw[px][v-1][2], w3=pw[px][v-1][3];
      int o0=po[px][v-1][0], o1=po[px][v-1][1];
      int o2=po[px][v-1][2], o3=po[px][v-1][3];
      float a=fb[(size_t)o0*CF+c];
      float b=fb[(size_t)o1*CF+c];
      float g=fb[(size_t)o2*CF+c];
      float h=fb[(size_t)o3*CF+c];
      float val=w0*a+w1*b+w2*g+w3*h;
      s[i]+=val; ss[i]+=val*val;
    }
  }
  unsigned short* cp=costb+(size_t)bid*WF*CF;
  #pragma unroll
  for (int i=0;i<10;i++){
    int px=i*8+slot;
    float mean=s[i]*0.2f;
    float var=ss[i]*0.2f-mean*mean;
    cp[(size_t)px*CF+c]=f2bf(var);
  }
}

// ---------------- reg1: conv3d 32->8 + relu via MFMA bf16 ----------------
// One wave per (d,y) row. M=16 x-px per tile (5 tiles), N=16 (8 oc + pad),
// K=32 ic per tap, 27 taps. A-frag: lane row=x (lane&15), k=(lane>>4)*8+j ->
// one 16B load from bf16 (d,y,x,ic) layout; wave load = 1KB contiguous. No LDS.
__global__ __launch_bounds__(256) void k_reg1(const unsigned short* __restrict__ costb,
    const unsigned short* __restrict__ wb, const float* __restrict__ bias, float* __restrict__ r1) {
  int bid=blockIdx.x;
  int sb=(bid&7)*256+(bid>>3);          // XCD swizzle: 256 contiguous blocks per XCD
  int tid=threadIdx.x;
  int row=sb*4+(tid>>6);                // 0..8191 = d*64+y
  int d=row>>6; int y=row&63;
  int lane=tid&63;
  int m=lane&15, g=lane>>4;
  float binit=(m<8)? bias[m] : 0.0f;
  f32x4 acc[5];
  #pragma unroll
  for (int t=0;t<5;t++) acc[t]={binit,binit,binit,binit};
  for (int kd=0;kd<3;kd++){
    int dd=d-1+kd; if (dd<0||dd>=DH) continue;
    for (int kh=0;kh<3;kh++){
      int yy=y-1+kh; if (yy<0||yy>=HF) continue;
      const unsigned short* rowbase=costb+(size_t)(dd*HF+yy)*WF*CF;
      #pragma unroll
      for (int kw=0;kw<3;kw++){
        int tap=(kd*3+kh)*3+kw;
        bf16x8 bfrag=*(const bf16x8*)(wb+(size_t)tap*512+lane*8);
        #pragma unroll
        for (int t=0;t<5;t++){
          int x=t*16+m+kw-1;
          int xc=iclamp(x,0,WF-1);
          bf16x8 afrag=*(const bf16x8*)(rowbase+(size_t)xc*CF+g*8);
          if (x!=xc){ bf16x8 z={0,0,0,0,0,0,0,0}; afrag=z; }
          acc[t]=__builtin_amdgcn_mfma_f32_16x16x32_bf16(afrag,bfrag,acc[t],0,0,0);
        }
      }
    }
  }
  if (m<8){
    float* op=r1+((size_t)(d*HF+y)*8+m)*WF+g*4;
    #pragma unroll
    for (int t=0;t<5;t++){
      float4 o;
      o.x=fmaxf(acc[t][0],0.0f); o.y=fmaxf(acc[t][1],0.0f);
      o.z=fmaxf(acc[t][2],0.0f); o.w=fmaxf(acc[t][3],0.0f);
      *(float4*)(op+t*16)=o;
    }
  }
}

// ---------------- reg2: conv3d 8->1, d-pair per thread, runtime plane loop ----------------
__global__ __launch_bounds__(256) void k_reg2(const float* __restrict__ r1,
    const float* __restrict__ w, const float* __restrict__ bias, float* __restrict__ c2) {
  __shared__ float wl[216]; // raw (1,8,3,3,3): [c][kd][kh][kw]
  int tid=threadIdx.x;
  for (int i=tid;i<216;i+=256) wl[i]=w[i];
  __syncthreads();
  int bid=blockIdx.x;
  int sb=(bid&7)*160+(bid>>3);
  int t=sb*256+tid;
  int x=t%80; int y=(t/80)&63; int dq=t/5120;
  int d0=dq*2;
  float acc0=bias[0], acc1=bias[0];
  for (int pi=0;pi<4;pi++){
    int dd=d0-1+pi; if (dd<0||dd>=DH) continue;
    bool do0=(pi<3), do1=(pi>0);
    for (int kh=0;kh<3;kh++){
      int yy=y-1+kh; if(yy<0||yy>=HF) continue;
      const float* base=r1+((size_t)(dd*HF+yy)*8)*WF+x;
      #pragma unroll
      for (int c=0;c<8;c++){
        const float* rr=base+(size_t)c*WF;
        float in_[3];
        in_[0]=(x>0)?rr[-1]:0.f; in_[1]=rr[0]; in_[2]=(x<79)?rr[1]:0.f;
        #pragma unroll
        for (int kw=0;kw<3;kw++){
          float v=in_[kw];
          if (do0) acc0+=v*wl[((c*3+pi)*3+kh)*3+kw];
          if (do1) acc1+=v*wl[((c*3+pi-1)*3+kh)*3+kw];
        }
      }
    }
  }
  c2[(size_t)d0*NFP+y*WF+x]=acc0;
  c2[(size_t)(d0+1)*NFP+y*WF+x]=acc1;
}

// ---------------- softmax over depth: 32 lanes per pixel ----------------
__global__ __launch_bounds__(256) void k_softmax(const float* __restrict__ c2,
    float* __restrict__ reglow, float* __restrict__ conflow){
  int tid=threadIdx.x;
  int lane=tid&31;
  int p=blockIdx.x*8+(tid>>5);
  const float* cp=c2+p;
  float c[4];
  #pragma unroll
  for (int j=0;j<4;j++) c[j]=cp[(size_t)(lane*4+j)*NFP];
  float m=fmaxf(fmaxf(c[0],c[1]),fmaxf(c[2],c[3]));
  #pragma unroll
  for (int off=1;off<32;off<<=1) m=fmaxf(m,__shfl_xor(m,off));
  float e[4]; float sum=0.f,sumd=0.f;
  #pragma unroll
  for (int j=0;j<4;j++){
    int d=lane*4+j;
    e[j]=expf(c[j]-m);
    sum+=e[j];
    float depth=1.0f/(2.0f-(float)d*(1.8f/127.0f));
    sumd+=e[j]*depth;
  }
  #pragma unroll
  for (int off=1;off<32;off<<=1){ sum+=__shfl_xor(sum,off); sumd+=__shfl_xor(sumd,off); }
  int wl=tid&63;
  float em1=__shfl(e[3],wl-1); if(lane==0) em1=0.f;
  float en0=__shfl(e[0],wl+1); if(lane==31) en0=0.f;
  float en1=__shfl(e[1],wl+1); if(lane==31) en1=0.f;
  float w0=em1 +e[0]+e[1]+e[2];
  float w1=e[0]+e[1]+e[2]+e[3];
  float w2=e[1]+e[2]+e[3]+en0;
  float w3=e[2]+e[3]+en0+en1;
  float mw=fmaxf(fmaxf(w0,w1),fmaxf(w2,w3));
  #pragma unroll
  for (int off=1;off<32;off<<=1) mw=fmaxf(mw,__shfl_xor(mw,off));
  if (lane==0){
    reglow[p]=sumd/sum;
    conflow[p]=mw/sum;
  }
}

// ---------------- x8 bilinear upsample (half-pixel, edge clamp) ----------------
__global__ __launch_bounds__(256) void k_upsample(const float* __restrict__ conflow,
    const float* __restrict__ reglow, float* __restrict__ outconf, float* __restrict__ regup){
  int t=blockIdx.x*256+threadIdx.x;
  int plane=t/NPIX; int p=t%NPIX;
  int oy=p/WIMG, ox=p%WIMG;
  float sy=((float)oy+0.5f)*0.125f-0.5f;
  float sx=((float)ox+0.5f)*0.125f-0.5f;
  float fy=floorf(sy), fx=floorf(sx);
  float wy=sy-fy, wx=sx-fx;
  int y0=(int)fy, x0=(int)fx;
  int y0c=iclamp(y0,0,HF-1), y1c=iclamp(y0+1,0,HF-1);
  int x0c=iclamp(x0,0,WF-1), x1c=iclamp(x0+1,0,WF-1);
  const float* s = plane? reglow : conflow;
  float v = s[y0c*WF+x0c]*(1.0f-wx)*(1.0f-wy)+s[y0c*WF+x1c]*wx*(1.0f-wy)
          + s[y1c*WF+x0c]*(1.0f-wx)*wy + s[y1c*WF+x1c]*wx*wy;
  if (plane==0) outconf[p]=v; else regup[p]=v;
}

// ---------------- fused refinement: conv1(4->32,relu) in LDS, conv2(32->1), add ----------------
__global__ __launch_bounds__(256) void k_refine(const float* __restrict__ img,
    const float* __restrict__ regup,
    const float* __restrict__ w1, const float* __restrict__ b1,
    const float* __restrict__ w2, const float* __restrict__ b2,
    float* __restrict__ outref){
  __shared__ __align__(16) float wl1[1152]; // [tap][ic][oc]
  __shared__ float wl2[288];               // [tap][ic]
  __shared__ float bl1[32];
  __shared__ float hid[32*18*20];          // [oc][hy][hx pad20]
  int tid=threadIdx.x;
  for (int i=tid;i<1152;i+=256){
    int oc=i&31; int rest=i>>5; int ic=rest&3; int tap=rest>>2;
    wl1[i]=w1[(oc*4+ic)*9+tap];
  }
  for (int i=tid;i<288;i+=256){
    int ic=i&31; int tap=i>>5;
    wl2[i]=w2[ic*9+tap];
  }
  if (tid<32) bl1[tid]=b1[tid];
  __syncthreads();
  int bx=blockIdx.x, by=blockIdx.y;
  // phase 1: hidden 18x18 tile (origin -1,-1 rel. to out tile)
  for (int i=tid;i<324;i+=256){
    int hy=i/18, hx=i%18;
    int gy=by*16-1+hy, gx=bx*16-1+hx;
    float a[32];
    if (gy<0||gy>=HIMG||gx<0||gx>=WIMG){
      #pragma unroll
      for (int oc=0;oc<32;oc++) a[oc]=0.0f;
    } else {
      #pragma unroll
      for (int oc=0;oc<32;oc++) a[oc]=bl1[oc];
      #pragma unroll
      for (int ky=0;ky<3;ky++){
        int iy=gy-1+ky; if(iy<0||iy>=HIMG) continue;
        #pragma unroll
        for (int kx=0;kx<3;kx++){
          int ix=gx-1+kx; if(ix<0||ix>=WIMG) continue;
          int tap=ky*3+kx;
          #pragma unroll
          for (int ic=0;ic<4;ic++){
            float v=(ic<3)? img[(size_t)ic*NPIX+(size_t)iy*WIMG+ix]
                          : regup[(size_t)iy*WIMG+ix];
            const float4* wv=(const float4*)&wl1[(tap*4+ic)*32];
            #pragma unroll
            for (int q=0;q<8;q++){
              float4 ww=wv[q];
              a[4*q+0]+=v*ww.x; a[4*q+1]+=v*ww.y;
              a[4*q+2]+=v*ww.z; a[4*q+3]+=v*ww.w;
            }
          }
        }
      }
      #pragma unroll
      for (int oc=0;oc<32;oc++) a[oc]=fmaxf(a[oc],0.0f);
    }
    #pragma unroll
    for (int oc=0;oc<32;oc++) hid[oc*360+hy*20+hx]=a[oc];
  }
  __syncthreads();
  // phase 2: conv2 32->1 from LDS
  int ty=tid>>4, tx=tid&15;
  float acc=b2[0];
  for (int c=0;c<32;c++){
    const float* hb=&hid[c*360];
    #pragma unroll
    for (int ky=0;ky<3;ky++){
      #pragma unroll
      for (int kx=0;kx<3;kx++){
        acc+=hb[(ty+ky)*20+(tx+kx)]*wl2[(ky*3+kx)*32+c];
      }
    }
  }
  int gy=by*16+ty, gx=bx*16+tx;
  size_t p=(size_t)gy*WIMG+gx;
  outref[p]=regup[p]+acc;
}

extern "C" void kernel_launch(void* const* d_in, const int* in_sizes, int n_in,
                              void* d_out, int out_size, void* d_ws, size_t ws_size,
                              hipStream_t stream) {
  (void)in_sizes; (void)n_in; (void)out_size; (void)ws_size;
  const float* images=(const float*)d_in[0];
  const float* Kmat  =(const float*)d_in[1];
  const float* poses =(const float*)d_in[2];
  const float* enc_w1=(const float*)d_in[3];
  const float* enc_b1=(const float*)d_in[4];
  const float* enc_w2=(const float*)d_in[5];
  const float* enc_b2=(const float*)d_in[6];
  const float* enc_w3=(const float*)d_in[7];
  const float* enc_b3=(const float*)d_in[8];
  const float* reg_w1=(const float*)d_in[9];
  const float* reg_b1=(const float*)d_in[10];
  const float* reg_w2=(const float*)d_in[11];
  const float* reg_b2=(const float*)d_in[12];
  const float* ref_w1=(const float*)d_in[13];
  const float* ref_b1=(const float*)d_in[14];
  const float* ref_w2=(const float*)d_in[15];
  const float* ref_b2=(const float*)d_in[16];
  float* ws=(float*)d_ws;
  float* out=(float*)d_out;

  k_setup<<<1,64,0,stream>>>(Kmat,poses,ws+OFF_WP);
  k_wprep<<<1,256,0,stream>>>(reg_w1,(unsigned short*)(ws+OFF_WB));
  k_conv1<<<1600,256,0,stream>>>(images,enc_w1,enc_b1,ws+OFF_X1);
  k_conv2<<<400,256,0,stream>>>(ws+OFF_X1,enc_w2,enc_b2,ws+OFF_X2);
  k_conv3<<<200,256,0,stream>>>(ws+OFF_X2,enc_w3,enc_b3,ws+OFF_FE);
  k_costvol<<<8192,256,0,stream>>>(ws+OFF_FE,ws+OFF_WP,(unsigned short*)(ws+OFF_COST));
  k_reg1<<<2048,256,0,stream>>>((const unsigned short*)(ws+OFF_COST),
                                (const unsigned short*)(ws+OFF_WB),reg_b1,ws+OFF_R1);
  k_reg2<<<1280,256,0,stream>>>(ws+OFF_R1,reg_w2,reg_b2,ws+OFF_C2);
  k_softmax<<<640,256,0,stream>>>(ws+OFF_C2,ws+OFF_RL,ws+OFF_CL);
  k_upsample<<<2560,256,0,stream>>>(ws+OFF_CL,ws+OFF_RL,out,ws+OFF_RU);
  k_refine<<<dim3(40,32),256,0,stream>>>(images,ws+OFF_RU,ref_w1,ref_b1,ref_w2,ref_b2,out+NPIX);
}

// Round 10
// 395.486 us; speedup vs baseline: 2.0065x; 1.1724x over previous
//
#include <hip/hip_runtime.h>
#include <math.h>

#define HIMG 512
#define WIMG 640
#define NPIX (HIMG*WIMG)      // 327680
#define HF 64
#define WF 80
#define NFP (HF*WF)           // 5120
#define DH 128
#define CF 32
#define NV 5

// ---- workspace layout (float offsets) ----
#define SZ_X1   (5u*8u*256u*320u)        // 3,276,800
#define SZ_X2   (5u*16u*128u*160u)       // 1,638,400
#define SZ_FE   (5u*NFP*CF)              // 819,200
#define SZ_WP   48u
#define SZ_COST ((unsigned)DH*HF*CF*WF)  // 20,971,520 elements (stored as bf16: half the floats)
#define SZ_R1   ((unsigned)DH*HF*8u*WF)  // 5,242,880
#define SZ_C2   ((unsigned)DH*NFP)       // 655,360

#define OFF_X1   0u
#define OFF_X2   (OFF_X1+SZ_X1)
#define OFF_FE   (OFF_X2+SZ_X2)
#define OFF_WP   (OFF_FE+SZ_FE)
#define OFF_COST (OFF_WP+SZ_WP)
#define OFF_R1   (OFF_COST+SZ_COST)
#define OFF_C2   (OFF_R1+SZ_R1)
#define OFF_RL   (OFF_C2+SZ_C2)
#define OFF_CL   (OFF_RL+NFP)
#define OFF_RU   (OFF_CL+NFP)
#define OFF_WB   (OFF_RU+NPIX)   // bf16 B-fragments for reg1 MFMA (27 taps x 1KB)

typedef __attribute__((ext_vector_type(8))) short bf16x8;
typedef __attribute__((ext_vector_type(4))) float f32x4;

__device__ __forceinline__ int iclamp(int v, int lo, int hi){ return v<lo?lo:(v>hi?hi:v); }

__device__ __forceinline__ unsigned short f2bf(float f){
  union { float f; unsigned u; } v; v.f=f;
  unsigned r=v.u+0x7fffu+((v.u>>16)&1u);
  return (unsigned short)(r>>16);
}

// ---------------- homography setup (1 thread) ----------------
__global__ void k_setup(const float* __restrict__ Kin, const float* __restrict__ poses,
                        float* __restrict__ warp) {
  if (threadIdx.x != 0 || blockIdx.x != 0) return;
  float Kf[9];
  for (int i=0;i<9;i++) Kf[i]=Kin[i];
  for (int i=0;i<6;i++) Kf[i]*=0.125f;
  float a=Kf[0],b=Kf[1],c=Kf[2],d=Kf[3],e=Kf[4],f=Kf[5],g=Kf[6],h=Kf[7],ii=Kf[8];
  float det=a*(e*ii-f*h)-b*(d*ii-f*g)+c*(d*h-e*g);
  float id=1.0f/det;
  float Ki[9]={(e*ii-f*h)*id,(c*h-b*ii)*id,(b*f-c*e)*id,
               (f*g-d*ii)*id,(a*ii-c*g)*id,(c*d-a*f)*id,
               (d*h-e*g)*id,(b*g-a*h)*id,(a*e-b*d)*id};
  float R0[9]={poses[0],poses[1],poses[2],poses[4],poses[5],poses[6],poses[8],poses[9],poses[10]};
  float t0[3]={poses[3],poses[7],poses[11]};
  for (int v=1; v<NV; v++) {
    const float* P=poses+16*v;
    float Rv[9]={P[0],P[1],P[2],P[4],P[5],P[6],P[8],P[9],P[10]};
    float tv[3]={P[3],P[7],P[11]};
    float TR[9], Tt[3], M[9], A[9], bb[3];
    for (int r=0;r<3;r++)
      for (int cc=0;cc<3;cc++)
        TR[r*3+cc]=Rv[r*3+0]*R0[cc*3+0]+Rv[r*3+1]*R0[cc*3+1]+Rv[r*3+2]*R0[cc*3+2];
    for (int r=0;r<3;r++)
      Tt[r]=tv[r]-(TR[r*3+0]*t0[0]+TR[r*3+1]*t0[1]+TR[r*3+2]*t0[2]);
    for (int r=0;r<3;r++)
      for (int cc=0;cc<3;cc++)
        M[r*3+cc]=TR[r*3+0]*Ki[0*3+cc]+TR[r*3+1]*Ki[1*3+cc]+TR[r*3+2]*Ki[2*3+cc];
    for (int r=0;r<3;r++)
      for (int cc=0;cc<3;cc++)
        A[r*3+cc]=Kf[r*3+0]*M[0*3+cc]+Kf[r*3+1]*M[1*3+cc]+Kf[r*3+2]*M[2*3+cc];
    for (int r=0;r<3;r++)
      bb[r]=Kf[r*3+0]*Tt[0]+Kf[r*3+1]*Tt[1]+Kf[r*3+2]*Tt[2];
    float* o=warp+(v-1)*12;
    for (int i=0;i<9;i++) o[i]=A[i];
    for (int r=0;r<3;r++) o[9+r]=bb[r];
  }
}

// ---------------- pack reg1 weights into bf16 B-fragments ----------------
__global__ void k_wprep(const float* __restrict__ w, unsigned short* __restrict__ wb){
  int tid=blockIdx.x*256+threadIdx.x;
  for (int idx=tid; idx<13824; idx+=256){
    int tap=idx>>9; int r=idx&511;
    int lane=r>>3; int j=r&7;
    int n=lane&15; int k=(lane>>4)*8+j;
    int kd=tap/9; int kh=(tap/3)%3; int kw=tap%3;
    float val=(n<8)? w[(((n*32+k)*3+kd)*3+kh)*3+kw] : 0.0f;
    wb[idx]=f2bf(val);
  }
}

// ---------------- encoder conv1: 3->8 stride2, relu ----------------
__global__ __launch_bounds__(256) void k_conv1(const float* __restrict__ img,
    const float* __restrict__ w, const float* __restrict__ bias, float* __restrict__ x1) {
  __shared__ float wl[216];
  int tid=threadIdx.x;
  for (int i=tid;i<216;i+=256){
    int oc=i&7; int rest=i>>3; int kx=rest%3; int ky=(rest/3)%3; int ic=rest/9;
    wl[i]=w[((oc*3+ic)*3+ky)*3+kx];
  }
  __syncthreads();
  int t=blockIdx.x*256+tid;
  int n=t/81920; int r=t%81920; int oy=r/320; int ox=r%320;
  float acc[8];
  #pragma unroll
  for (int oc=0;oc<8;oc++) acc[oc]=bias[oc];
  for (int ic=0;ic<3;ic++){
    const float* ip = img + (n*3+ic)*NPIX;
    #pragma unroll
    for (int ky=0;ky<3;ky++){
      int iy=2*oy+ky; if (iy>=HIMG) continue;
      #pragma unroll
      for (int kx=0;kx<3;kx++){
        int ix=2*ox+kx; if (ix>=WIMG) continue;
        float v=ip[iy*WIMG+ix];
        const float* ww=&wl[((ic*3+ky)*3+kx)*8];
        #pragma unroll
        for (int oc=0;oc<8;oc++) acc[oc]+=v*ww[oc];
      }
    }
  }
  float* op = x1 + (n*8)*81920 + oy*320+ox;
  #pragma unroll
  for (int oc=0;oc<8;oc++){ float vv=fmaxf(acc[oc],0.0f); op[oc*81920]=vv; }
}

// ---------------- encoder conv2: 8->16 stride2, relu ----------------
__global__ __launch_bounds__(256) void k_conv2(const float* __restrict__ x1,
    const float* __restrict__ w, const float* __restrict__ bias, float* __restrict__ x2){
  __shared__ float wl[1152];
  int tid=threadIdx.x;
  for (int i=tid;i<1152;i+=256){
    int oc=i&15; int rest=i>>4; int tap=rest%9; int ic=rest/9;
    int ky=tap/3, kx=tap%3;
    wl[i]=w[((oc*8+ic)*3+ky)*3+kx];
  }
  __syncthreads();
  int t=blockIdx.x*256+tid;
  int n=t/20480; int r=t%20480; int oy=r/160; int ox=r%160;
  float acc[16];
  #pragma unroll
  for (int oc=0;oc<16;oc++) acc[oc]=bias[oc];
  for (int ic=0;ic<8;ic++){
    const float* ip=x1+(n*8+ic)*81920;
    #pragma unroll
    for (int ky=0;ky<3;ky++){
      int iy=2*oy+ky; if(iy>=256) continue;
      #pragma unroll
      for (int kx=0;kx<3;kx++){
        int ix=2*ox+kx; if(ix>=320) continue;
        float v=ip[iy*320+ix];
        const float* ww=&wl[(ic*9+ky*3+kx)*16];
        #pragma unroll
        for (int oc=0;oc<16;oc++) acc[oc]+=v*ww[oc];
      }
    }
  }
  float* op=x2+(n*16)*20480+oy*160+ox;
  #pragma unroll
  for (int oc=0;oc<16;oc++){ float vv=fmaxf(acc[oc],0.0f); op[oc*20480]=vv; }
}

// ---------------- encoder conv3: 16->32 stride2, oc-split x2, channel-last out ----------------
__global__ __launch_bounds__(256) void k_conv3(const float* __restrict__ x2,
    const float* __restrict__ w, const float* __restrict__ bias, float* __restrict__ fe){
  __shared__ float wl[4608];
  int tid=threadIdx.x;
  for (int i=tid;i<4608;i+=256){
    int oc=i&31; int rest=i>>5; int tap=rest%9; int ic=rest/9;
    int ky=tap/3,kx=tap%3;
    wl[i]=w[((oc*16+ic)*3+ky)*3+kx];
  }
  __syncthreads();
  int t=blockIdx.x*256+tid;          // 51200
  int half=t&1; int r=t>>1;          // r: 0..25599
  int n=r/NFP; int p=r%NFP; int oy=p/WF; int ox=p%WF;
  float acc[16];
  #pragma unroll
  for (int oc=0;oc<16;oc++) acc[oc]=bias[half*16+oc];
  for (int ic=0;ic<16;ic++){
    const float* ip=x2+(n*16+ic)*20480;
    #pragma unroll
    for (int ky=0;ky<3;ky++){
      int iy=2*oy+ky; if(iy>=128) continue;
      #pragma unroll
      for (int kx=0;kx<3;kx++){
        int ix=2*ox+kx; if(ix>=160) continue;
        float v=ip[iy*160+ix];
        const float* ww=&wl[(ic*9+ky*3+kx)*32+half*16];
        #pragma unroll
        for (int oc=0;oc<16;oc++) acc[oc]+=v*ww[oc];
      }
    }
  }
  float* op=fe+(size_t)r*CF+half*16;
  #pragma unroll
  for (int q=0;q<4;q++) ((float4*)op)[q]=((float4*)acc)[q];
}

// ---------------- plane-sweep cost volume, channel-major gathers, bf16 (d,y,x,ic) out ----------------
__global__ __launch_bounds__(256) void k_costvol(const float* __restrict__ fe,
    const float* __restrict__ warp, unsigned short* __restrict__ costb){
  __shared__ float pw[80][4][4];   // [px][view-1][w00,w01,w10,w11]
  __shared__ int   po[80][4][4];   // [px][view-1][corner px-offset]
  int bid=blockIdx.x;              // 0..8191 = d*64+y
  int d=bid>>6; int y=bid&63;
  int tid=threadIdx.x;
  float invd=2.0f-(float)d*(1.8f/127.0f);
  float depth=1.0f/invd;
  if (tid<80){
    int x=tid;
    float fx=(float)x, fy=(float)y;
    for (int v=1; v<NV; v++){
      const float* W=warp+(v-1)*12;
      float u_=depth*(W[0]*fx+W[1]*fy+W[2])+W[9];
      float v_=depth*(W[3]*fx+W[4]*fy+W[5])+W[10];
      float z_=depth*(W[6]*fx+W[7]*fy+W[8])+W[11];
      float valid=(z_>0.001f)?1.0f:0.0f;
      float zc=(z_>0.001f)?z_:0.001f;
      float uu=u_/zc, vv=v_/zc;
      float fx0=floorf(uu), fy0=floorf(vv);
      float wx=uu-fx0, wy=vv-fy0;
      int xi=(int)fx0, yi=(int)fy0;
      float m00=((xi>=0)&&(xi<WF)&&(yi>=0)&&(yi<HF))?valid:0.0f;
      float m01=((xi+1>=0)&&(xi+1<WF)&&(yi>=0)&&(yi<HF))?valid:0.0f;
      float m10=((xi>=0)&&(xi<WF)&&(yi+1>=0)&&(yi+1<HF))?valid:0.0f;
      float m11=((xi+1>=0)&&(xi+1<WF)&&(yi+1>=0)&&(yi+1<HF))?valid:0.0f;
      pw[x][v-1][0]=(1.0f-wx)*(1.0f-wy)*m00;
      pw[x][v-1][1]=wx*(1.0f-wy)*m01;
      pw[x][v-1][2]=(1.0f-wx)*wy*m10;
      pw[x][v-1][3]=wx*wy*m11;
      int xc0=iclamp(xi,0,WF-1), xc1=iclamp(xi+1,0,WF-1);
      int yc0=iclamp(yi,0,HF-1), yc1=iclamp(yi+1,0,HF-1);
      po[x][v-1][0]=yc0*WF+xc0;
      po[x][v-1][1]=yc0*WF+xc1;
      po[x][v-1][2]=yc1*WF+xc0;
      po[x][v-1][3]=yc1*WF+xc1;
    }
  }
  __syncthreads();
  int c=tid&31, slot=tid>>5;
  float s[10], ss[10];
  #pragma unroll
  for (int i=0;i<10;i++){
    int px=i*8+slot;
    float r=fe[(size_t)(y*WF+px)*CF+c];
    s[i]=r; ss[i]=r*r;
  }
  for (int v=1; v<NV; v++){
    const float* fb=fe+(size_t)v*NFP*CF;
    #pragma unroll
    for (int i=0;i<10;i++){
      int px=i*8+slot;
      float w0=pw[px][v-1][0], w1=pw[px][v-1][1];
      float w2=pw[px][v-1][2], w3=pw[px][v-1][3];
      int o0=po[px][v-1][0], o1=po[px][v-1][1];
      int o2=po[px][v-1][2], o3=po[px][v-1][3];
      float a=fb[(size_t)o0*CF+c];
      float b=fb[(size_t)o1*CF+c];
      float g=fb[(size_t)o2*CF+c];
      float h=fb[(size_t)o3*CF+c];
      float val=w0*a+w1*b+w2*g+w3*h;
      s[i]+=val; ss[i]+=val*val;
    }
  }
  unsigned short* cp=costb+(size_t)bid*WF*CF;
  #pragma unroll
  for (int i=0;i<10;i++){
    int px=i*8+slot;
    float mean=s[i]*0.2f;
    float var=ss[i]*0.2f-mean*mean;
    cp[(size_t)px*CF+c]=f2bf(var);
  }
}

// ---------------- reg1: conv3d 32->8 + relu via MFMA bf16 ----------------
__global__ __launch_bounds__(256) void k_reg1(const unsigned short* __restrict__ costb,
    const unsigned short* __restrict__ wb, const float* __restrict__ bias, float* __restrict__ r1) {
  int bid=blockIdx.x;
  int sb=(bid&7)*256+(bid>>3);
  int tid=threadIdx.x;
  int row=sb*4+(tid>>6);                // 0..8191 = d*64+y
  int d=row>>6; int y=row&63;
  int lane=tid&63;
  int m=lane&15, g=lane>>4;
  float binit=(m<8)? bias[m] : 0.0f;
  f32x4 acc[5];
  #pragma unroll
  for (int t=0;t<5;t++) acc[t]={binit,binit,binit,binit};
  for (int kd=0;kd<3;kd++){
    int dd=d-1+kd; if (dd<0||dd>=DH) continue;
    for (int kh=0;kh<3;kh++){
      int yy=y-1+kh; if (yy<0||yy>=HF) continue;
      const unsigned short* rowbase=costb+(size_t)(dd*HF+yy)*WF*CF;
      #pragma unroll
      for (int kw=0;kw<3;kw++){
        int tap=(kd*3+kh)*3+kw;
        bf16x8 bfrag=*(const bf16x8*)(wb+(size_t)tap*512+lane*8);
        #pragma unroll
        for (int t=0;t<5;t++){
          int x=t*16+m+kw-1;
          int xc=iclamp(x,0,WF-1);
          bf16x8 afrag=*(const bf16x8*)(rowbase+(size_t)xc*CF+g*8);
          if (x!=xc){ bf16x8 z={0,0,0,0,0,0,0,0}; afrag=z; }
          acc[t]=__builtin_amdgcn_mfma_f32_16x16x32_bf16(afrag,bfrag,acc[t],0,0,0);
        }
      }
    }
  }
  if (m<8){
    float* op=r1+((size_t)(d*HF+y)*8+m)*WF+g*4;
    #pragma unroll
    for (int t=0;t<5;t++){
      float4 o;
      o.x=fmaxf(acc[t][0],0.0f); o.y=fmaxf(acc[t][1],0.0f);
      o.z=fmaxf(acc[t][2],0.0f); o.w=fmaxf(acc[t][3],0.0f);
      *(float4*)(op+t*16)=o;
    }
  }
}

// ---------------- reg2: conv3d 8->1, d-pair per thread, runtime plane loop ----------------
__global__ __launch_bounds__(256) void k_reg2(const float* __restrict__ r1,
    const float* __restrict__ w, const float* __restrict__ bias, float* __restrict__ c2) {
  __shared__ float wl[216]; // raw (1,8,3,3,3): [c][kd][kh][kw]
  int tid=threadIdx.x;
  for (int i=tid;i<216;i+=256) wl[i]=w[i];
  __syncthreads();
  int bid=blockIdx.x;
  int sb=(bid&7)*160+(bid>>3);
  int t=sb*256+tid;
  int x=t%80; int y=(t/80)&63; int dq=t/5120;
  int d0=dq*2;
  float acc0=bias[0], acc1=bias[0];
  for (int pi=0;pi<4;pi++){
    int dd=d0-1+pi; if (dd<0||dd>=DH) continue;
    bool do0=(pi<3), do1=(pi>0);
    for (int kh=0;kh<3;kh++){
      int yy=y-1+kh; if(yy<0||yy>=HF) continue;
      const float* base=r1+((size_t)(dd*HF+yy)*8)*WF+x;
      #pragma unroll
      for (int c=0;c<8;c++){
        const float* rr=base+(size_t)c*WF;
        float in_[3];
        in_[0]=(x>0)?rr[-1]:0.f; in_[1]=rr[0]; in_[2]=(x<79)?rr[1]:0.f;
        #pragma unroll
        for (int kw=0;kw<3;kw++){
          float v=in_[kw];
          if (do0) acc0+=v*wl[((c*3+pi)*3+kh)*3+kw];
          if (do1) acc1+=v*wl[((c*3+pi-1)*3+kh)*3+kw];
        }
      }
    }
  }
  c2[(size_t)d0*NFP+y*WF+x]=acc0;
  c2[(size_t)(d0+1)*NFP+y*WF+x]=acc1;
}

// ---------------- softmax over depth: 32 lanes per pixel ----------------
__global__ __launch_bounds__(256) void k_softmax(const float* __restrict__ c2,
    float* __restrict__ reglow, float* __restrict__ conflow){
  int tid=threadIdx.x;
  int lane=tid&31;
  int p=blockIdx.x*8+(tid>>5);
  const float* cp=c2+p;
  float c[4];
  #pragma unroll
  for (int j=0;j<4;j++) c[j]=cp[(size_t)(lane*4+j)*NFP];
  float m=fmaxf(fmaxf(c[0],c[1]),fmaxf(c[2],c[3]));
  #pragma unroll
  for (int off=1;off<32;off<<=1) m=fmaxf(m,__shfl_xor(m,off));
  float e[4]; float sum=0.f,sumd=0.f;
  #pragma unroll
  for (int j=0;j<4;j++){
    int d=lane*4+j;
    e[j]=expf(c[j]-m);
    sum+=e[j];
    float depth=1.0f/(2.0f-(float)d*(1.8f/127.0f));
    sumd+=e[j]*depth;
  }
  #pragma unroll
  for (int off=1;off<32;off<<=1){ sum+=__shfl_xor(sum,off); sumd+=__shfl_xor(sumd,off); }
  int wl=tid&63;
  float em1=__shfl(e[3],wl-1); if(lane==0) em1=0.f;
  float en0=__shfl(e[0],wl+1); if(lane==31) en0=0.f;
  float en1=__shfl(e[1],wl+1); if(lane==31) en1=0.f;
  float w0=em1 +e[0]+e[1]+e[2];
  float w1=e[0]+e[1]+e[2]+e[3];
  float w2=e[1]+e[2]+e[3]+en0;
  float w3=e[2]+e[3]+en0+en1;
  float mw=fmaxf(fmaxf(w0,w1),fmaxf(w2,w3));
  #pragma unroll
  for (int off=1;off<32;off<<=1) mw=fmaxf(mw,__shfl_xor(mw,off));
  if (lane==0){
    reglow[p]=sumd/sum;
    conflow[p]=mw/sum;
  }
}

// ---------------- x8 bilinear upsample (half-pixel, edge clamp) ----------------
__global__ __launch_bounds__(256) void k_upsample(const float* __restrict__ conflow,
    const float* __restrict__ reglow, float* __restrict__ outconf, float* __restrict__ regup){
  int t=blockIdx.x*256+threadIdx.x;
  int plane=t/NPIX; int p=t%NPIX;
  int oy=p/WIMG, ox=p%WIMG;
  float sy=((float)oy+0.5f)*0.125f-0.5f;
  float sx=((float)ox+0.5f)*0.125f-0.5f;
  float fy=floorf(sy), fx=floorf(sx);
  float wy=sy-fy, wx=sx-fx;
  int y0=(int)fy, x0=(int)fx;
  int y0c=iclamp(y0,0,HF-1), y1c=iclamp(y0+1,0,HF-1);
  int x0c=iclamp(x0,0,WF-1), x1c=iclamp(x0+1,0,WF-1);
  const float* s = plane? reglow : conflow;
  float v = s[y0c*WF+x0c]*(1.0f-wx)*(1.0f-wy)+s[y0c*WF+x1c]*wx*(1.0f-wy)
          + s[y1c*WF+x0c]*(1.0f-wx)*wy + s[y1c*WF+x1c]*wx*wy;
  if (plane==0) outconf[p]=v; else regup[p]=v;
}

// ---------------- fused refinement v3: fp32 oc-chunked hidden, OOB-hidden zeroed ----------------
// Phase 0: stage 20x20x4 inputs. Loop cg=0..3: phase1 computes hid[324][8] fp32
// for oc cg*8..cg*8+7 (OOB hidden px = 0, matching SAME-pad conv2 semantics);
// phase2 accumulates chunk into per-output acc. All fp32. LDS ~22.6KB.
__global__ __launch_bounds__(256,4) void k_refine(const float* __restrict__ img,
    const float* __restrict__ regup,
    const float* __restrict__ w1, const float* __restrict__ b1,
    const float* __restrict__ w2, const float* __restrict__ b2,
    float* __restrict__ outref){
  __shared__ __align__(16) float wl1[1152];   // [tap][ic][oc]
  __shared__ __align__(16) float wl2[288];    // [tap][c]
  __shared__ float bl1[32];
  __shared__ __align__(16) float in_t[1600];  // [ic][20][20], origin (-2,-2)
  __shared__ __align__(16) float hidc[324*8]; // [px][8] current oc-chunk
  int tid=threadIdx.x;
  for (int i=tid;i<1152;i+=256){
    int oc=i&31; int rest=i>>5; int ic=rest&3; int tap=rest>>2;
    wl1[i]=w1[(oc*4+ic)*9+tap];
  }
  for (int i=tid;i<288;i+=256){
    int c=i&31; int tap=i>>5;
    wl2[i]=w2[c*9+tap];
  }
  if (tid<32) bl1[tid]=b1[tid];
  int bx=blockIdx.x, by=blockIdx.y;
  int gy0=by*16-2, gx0=bx*16-2;
  for (int i=tid;i<1600;i+=256){
    int ic=i/400; int r=i%400; int yy=r/20, xx=r%20;
    int gy=gy0+yy, gx=gx0+xx;
    float v=0.0f;
    if (gy>=0 && gy<HIMG && gx>=0 && gx<WIMG)
      v=(ic<3)? img[(size_t)ic*NPIX+(size_t)gy*WIMG+gx] : regup[(size_t)gy*WIMG+gx];
    in_t[i]=v;
  }
  int ty=tid>>4, tx=tid&15;
  float acc=b2[0];
  for (int cg=0; cg<4; ++cg){
    __syncthreads();   // staging done (cg=0) / prev chunk's phase-2 reads done
    for (int px=tid; px<324; px+=256){
      int hy=px/18, hx=px%18;
      int ghy=by*16-1+hy, ghx=bx*16-1+hx;
      float a[8];
      if (ghy<0||ghy>=HIMG||ghx<0||ghx>=WIMG){
        #pragma unroll
        for (int q=0;q<8;q++) a[q]=0.0f;   // hidden px outside image: conv2 SAME-pad reads 0
      } else {
        #pragma unroll
        for (int q=0;q<8;q++) a[q]=bl1[cg*8+q];
        #pragma unroll
        for (int ky=0;ky<3;ky++){
          #pragma unroll
          for (int kx=0;kx<3;kx++){
            int tap=ky*3+kx;
            const float* ip=&in_t[(hy+ky)*20+(hx+kx)];
            #pragma unroll
            for (int ic=0;ic<4;ic++){
              float v=ip[ic*400];
              const float4* wv=(const float4*)&wl1[(tap*4+ic)*32+cg*8];
              float4 w0=wv[0], w1v=wv[1];
              a[0]+=v*w0.x; a[1]+=v*w0.y; a[2]+=v*w0.z; a[3]+=v*w0.w;
              a[4]+=v*w1v.x; a[5]+=v*w1v.y; a[6]+=v*w1v.z; a[7]+=v*w1v.w;
            }
          }
        }
        #pragma unroll
        for (int q=0;q<8;q++) a[q]=fmaxf(a[q],0.0f);
      }
      float* hp=&hidc[px*8];
      ((float4*)hp)[0]=((float4*)a)[0];
      ((float4*)hp)[1]=((float4*)a)[1];
    }
    __syncthreads();
    #pragma unroll
    for (int ky=0;ky<3;ky++){
      #pragma unroll
      for (int kx=0;kx<3;kx++){
        const float* hp=&hidc[((ty+ky)*18+(tx+kx))*8];
        const float* w8=&wl2[(ky*3+kx)*32+cg*8];
        float4 h0=((const float4*)hp)[0], h1=((const float4*)hp)[1];
        acc+=h0.x*w8[0]+h0.y*w8[1]+h0.z*w8[2]+h0.w*w8[3]
            +h1.x*w8[4]+h1.y*w8[5]+h1.z*w8[6]+h1.w*w8[7];
      }
    }
  }
  int gy=by*16+ty, gx=bx*16+tx;
  size_t p=(size_t)gy*WIMG+gx;
  outref[p]=regup[p]+acc;
}

extern "C" void kernel_launch(void* const* d_in, const int* in_sizes, int n_in,
                              void* d_out, int out_size, void* d_ws, size_t ws_size,
                              hipStream_t stream) {
  (void)in_sizes; (void)n_in; (void)out_size; (void)ws_size;
  const float* images=(const float*)d_in[0];
  const float* Kmat  =(const float*)d_in[1];
  const float* poses =(const float*)d_in[2];
  const float* enc_w1=(const float*)d_in[3];
  const float* enc_b1=(const float*)d_in[4];
  const float* enc_w2=(const float*)d_in[5];
  const float* enc_b2=(const float*)d_in[6];
  const float* enc_w3=(const float*)d_in[7];
  const float* enc_b3=(const float*)d_in[8];
  const float* reg_w1=(const float*)d_in[9];
  const float* reg_b1=(const float*)d_in[10];
  const float* reg_w2=(const float*)d_in[11];
  const float* reg_b2=(const float*)d_in[12];
  const float* ref_w1=(const float*)d_in[13];
  const float* ref_b1=(const float*)d_in[14];
  const float* ref_w2=(const float*)d_in[15];
  const float* ref_b2=(const float*)d_in[16];
  float* ws=(float*)d_ws;
  float* out=(float*)d_out;

  k_setup<<<1,64,0,stream>>>(Kmat,poses,ws+OFF_WP);
  k_wprep<<<1,256,0,stream>>>(reg_w1,(unsigned short*)(ws+OFF_WB));
  k_conv1<<<1600,256,0,stream>>>(images,enc_w1,enc_b1,ws+OFF_X1);
  k_conv2<<<400,256,0,stream>>>(ws+OFF_X1,enc_w2,enc_b2,ws+OFF_X2);
  k_conv3<<<200,256,0,stream>>>(ws+OFF_X2,enc_w3,enc_b3,ws+OFF_FE);
  k_costvol<<<8192,256,0,stream>>>(ws+OFF_FE,ws+OFF_WP,(unsigned short*)(ws+OFF_COST));
  k_reg1<<<2048,256,0,stream>>>((const unsigned short*)(ws+OFF_COST),
                                (const unsigned short*)(ws+OFF_WB),reg_b1,ws+OFF_R1);
  k_reg2<<<1280,256,0,stream>>>(ws+OFF_R1,reg_w2,reg_b2,ws+OFF_C2);
  k_softmax<<<640,256,0,stream>>>(ws+OFF_C2,ws+OFF_RL,ws+OFF_CL);
  k_upsample<<<2560,256,0,stream>>>(ws+OFF_CL,ws+OFF_RL,out,ws+OFF_RU);
  k_refine<<<dim3(40,32),256,0,stream>>>(images,ws+OFF_RU,ref_w1,ref_b1,ref_w2,ref_b2,out+NPIX);
}